// Round 8
// baseline (1339.030 us; speedup 1.0000x reference)
//
#include <hip/hip_runtime.h>
#include <hip/hip_fp16.h>

// CorrectAndSmooth on MI355X.
// N=100000 nodes, C=48 classes, E=1.6M edges, 10+10 propagation layers.
// R7: CSR build write-amp fix: bucketed two-pass fill (stage into per-bucket
//     streams, then per-bucket LDS counting sort -> contiguous L2-local writes).
//     NS 3->4 (3.2MB slice window < 4MB XCD L2).

constexpr int NN  = 100000;
constexpr int NC  = 48;
constexpr int NE  = 1600000;
constexpr int NTR = 10000;
constexpr int NVA = 10000;
constexpr float ALPHA1 = 0.979f;
constexpr float ALPHA2 = 0.756f;
constexpr int ROWH = 64;           // halfs per padded row (128B)
constexpr int ROWB = 128;          // bytes per padded row

constexpr int NS = 4;                          // src slices
constexpr int SW = (NN + NS - 1) / NS;         // 25000
constexpr int N3 = NN * NS;                    // 400000 cells (d*NS+s)
constexpr int SCAN_B = 1024;
constexpr int NB3 = (N3 + SCAN_B - 1) / SCAN_B;   // 391
constexpr int NBUK = (NN + 255) / 256;            // 391 dst buckets
constexpr int NEB = (NTR * 12 + 255) / 256;       // k_error blocks

union H4 { uint2 u; __half2 h[2]; };

__device__ __forceinline__ float4 h4f(uint2 q) {
    H4 t; t.u = q;
    float2 a = __half22float2(t.h[0]), b = __half22float2(t.h[1]);
    return make_float4(a.x, a.y, b.x, b.y);
}
__device__ __forceinline__ uint2 f4h(float4 v) {
    H4 t;
    t.h[0] = __float22half2_rn(make_float2(v.x, v.y));
    t.h[1] = __float22half2_rn(make_float2(v.z, v.w));
    return t.u;
}

union H8 { uint4 u; __half2 h[4]; };

__device__ __forceinline__ void h8acc(uint4 q, float4& A, float4& B) {
    H8 t; t.u = q;
    float2 f0 = __half22float2(t.h[0]), f1 = __half22float2(t.h[1]);
    float2 f2 = __half22float2(t.h[2]), f3 = __half22float2(t.h[3]);
    A.x += f0.x; A.y += f0.y; A.z += f1.x; A.w += f1.y;
    B.x += f2.x; B.y += f2.y; B.z += f3.x; B.w += f3.y;
}

// ---------- preprocessing ----------

__global__ void k_count3(const int* __restrict__ src, const int* __restrict__ dst,
                         int* __restrict__ deg3) {
    int e = blockIdx.x * blockDim.x + threadIdx.x;
    if (e < NE) {
        int d = dst[e], s = src[e] / SW;
        atomicAdd(&deg3[d * NS + s], 1);
    }
}

__global__ void k_bsum(const int* __restrict__ deg3, int* __restrict__ bsum) {
    int base = blockIdx.x * SCAN_B + threadIdx.x * 4;
    int s = 0;
    if (base + 3 < N3) {
        int4 q = *reinterpret_cast<const int4*>(deg3 + base);
        s = q.x + q.y + q.z + q.w;
    } else {
#pragma unroll
        for (int i = 0; i < 4; ++i) if (base + i < N3) s += deg3[base + i];
    }
    for (int o = 32; o > 0; o >>= 1) s += __shfl_down(s, o, 64);
    __shared__ int sh[4];
    if ((threadIdx.x & 63) == 0) sh[threadIdx.x >> 6] = s;
    __syncthreads();
    if (threadIdx.x == 0) bsum[blockIdx.x] = sh[0] + sh[1] + sh[2] + sh[3];
}

__global__ void k_bscan(int* __restrict__ bsum) {
    __shared__ int sh[512];
    int t = threadIdx.x;
    int v = (t < NB3) ? bsum[t] : 0;
    sh[t] = v;
    __syncthreads();
    for (int o = 1; o < 512; o <<= 1) {
        int u = (t >= o) ? sh[t - o] : 0;
        __syncthreads();
        sh[t] += u;
        __syncthreads();
    }
    if (t < NB3) bsum[t] = sh[t] - v;
}

__global__ void k_scatter(const int* __restrict__ deg3, const int* __restrict__ boff,
                          int* __restrict__ rowp3) {
    int base = blockIdx.x * SCAN_B + threadIdx.x * 4;
    int v0 = 0, v1 = 0, v2 = 0, v3 = 0;
    if (base + 3 < N3) {
        int4 q = *reinterpret_cast<const int4*>(deg3 + base);
        v0 = q.x; v1 = q.y; v2 = q.z; v3 = q.w;
    } else {
        if (base     < N3) v0 = deg3[base];
        if (base + 1 < N3) v1 = deg3[base + 1];
        if (base + 2 < N3) v2 = deg3[base + 2];
        if (base + 3 < N3) v3 = deg3[base + 3];
    }
    int tsum = v0 + v1 + v2 + v3;
    int lane = threadIdx.x & 63, w = threadIdx.x >> 6;
    int inc = tsum;
    for (int o = 1; o < 64; o <<= 1) {
        int u = __shfl_up(inc, o, 64);
        if (lane >= o) inc += u;
    }
    __shared__ int wsum[4];
    if (lane == 63) wsum[w] = inc;
    __syncthreads();
    int woff = 0;
#pragma unroll
    for (int i = 0; i < 4; ++i) if (i < w) woff += wsum[i];
    int ex = boff[blockIdx.x] + woff + inc - tsum;
    if (base     < N3) rowp3[base]     = ex;
    if (base + 1 < N3) rowp3[base + 1] = ex + v0;
    if (base + 2 < N3) rowp3[base + 2] = ex + v0 + v1;
    if (base + 3 < N3) rowp3[base + 3] = ex + v0 + v1 + v2;
    if (blockIdx.x == 0 && threadIdx.x == 0) rowp3[N3] = NE;
}

__global__ void k_norm(const int* __restrict__ rowp3, float* __restrict__ norm) {
    int v = blockIdx.x * blockDim.x + threadIdx.x;
    if (v < NN) {
        int d = rowp3[(v + 1) * NS] - rowp3[v * NS];
        if (d < 1) d = 1;
        norm[v] = rsqrtf((float)d);
    }
}

// Pass A: stage packed edges into per-bucket streams.
// word = src | (cellLocal<<17), cellLocal = (d&255)*NS + slice  (10 bits)
__global__ void k_stage(const int* __restrict__ src, const int* __restrict__ dst,
                        const int* __restrict__ rowp3, int* __restrict__ bfill,
                        int* __restrict__ staged) {
    int e = blockIdx.x * blockDim.x + threadIdx.x;
    if (e < NE) {
        int sv = src[e], d = dst[e];
        int b = d >> 8;
        int cellLocal = ((d & 255) * NS) | (sv / SW);
        int pos = atomicAdd(&bfill[b], 1);
        staged[rowp3[b << 10] + pos] = sv | (cellLocal << 17);
    }
}

// Pass B: per-bucket LDS counting sort -> csr holds byte offsets (src*128)
__global__ __launch_bounds__(256)
void k_bsort(const int* __restrict__ staged, const int* __restrict__ rowp3,
             int* __restrict__ csr) {
    __shared__ int cnt[1024];
    __shared__ int wsum[4];
    int b = blockIdx.x, tid = threadIdx.x;
    int lo = rowp3[b << 10];
    int cellHi = (b + 1) << 10; if (cellHi > N3) cellHi = N3;
    int hi = rowp3[cellHi];
#pragma unroll
    for (int i = tid; i < 1024; i += 256) cnt[i] = 0;
    __syncthreads();
    for (int i = lo + tid; i < hi; i += 256)
        atomicAdd(&cnt[(staged[i] >> 17) & 1023], 1);
    __syncthreads();
    // exclusive scan of cnt[0..1023]
    int base4 = tid * 4;
    int c0 = cnt[base4], c1 = cnt[base4 + 1], c2 = cnt[base4 + 2], c3 = cnt[base4 + 3];
    int tsum = c0 + c1 + c2 + c3;
    int lane = tid & 63, w = tid >> 6;
    int inc = tsum;
    for (int o = 1; o < 64; o <<= 1) {
        int u = __shfl_up(inc, o, 64);
        if (lane >= o) inc += u;
    }
    if (lane == 63) wsum[w] = inc;
    __syncthreads();
    int woff = 0;
#pragma unroll
    for (int i = 0; i < 4; ++i) if (i < w) woff += wsum[i];
    int ex = woff + inc - tsum;
    __syncthreads();   // all reads of cnt done before overwrite
    cnt[base4]     = ex;
    cnt[base4 + 1] = ex + c0;
    cnt[base4 + 2] = ex + c0 + c1;
    cnt[base4 + 3] = ex + c0 + c1 + c2;
    __syncthreads();
    for (int i = lo + tid; i < hi; i += 256) {
        int u = staged[i];
        int pos = atomicAdd(&cnt[(u >> 17) & 1023], 1);
        csr[lo + pos] = (u & 0x1FFFF) * ROWB;
    }
}

// ---------- error build + sigma (two-stage, no global atomics) ----------
__global__ void k_error(const float* __restrict__ y_soft, const int* __restrict__ y_true,
                        const int* __restrict__ train, const float* __restrict__ norm,
                        __half* __restrict__ A, __half* __restrict__ last,
                        float* __restrict__ partial) {
    int t = blockIdx.x * blockDim.x + threadIdx.x;
    float a = 0.f;
    if (t < NTR * 12) {
        int j = t / 12, ch = (t % 12) * 4;
        int yt = y_true[j];
        float4 ys = *reinterpret_cast<const float4*>(y_soft + (size_t)j * NC + ch);
        float e0 = ((ch + 0 == yt) ? 1.f : 0.f) - ys.x;
        float e1 = ((ch + 1 == yt) ? 1.f : 0.f) - ys.y;
        float e2 = ((ch + 2 == yt) ? 1.f : 0.f) - ys.z;
        float e3 = ((ch + 3 == yt) ? 1.f : 0.f) - ys.w;
        int r = train[j];
        float w = norm[r];
        *reinterpret_cast<uint2*>(A + (size_t)r * ROWH + ch) =
            f4h(make_float4(w * e0, w * e1, w * e2, w * e3));
        float la = 1.0f - ALPHA1;
        *reinterpret_cast<uint2*>(last + (size_t)r * ROWH + ch) =
            f4h(make_float4(la * e0, la * e1, la * e2, la * e3));
        a = fabsf(e0) + fabsf(e1) + fabsf(e2) + fabsf(e3);
    }
    for (int o = 32; o > 0; o >>= 1) a += __shfl_down(a, o, 64);
    __shared__ float sh[4];
    if ((threadIdx.x & 63) == 0) sh[threadIdx.x >> 6] = a;
    __syncthreads();
    if (threadIdx.x == 0) partial[blockIdx.x] = sh[0] + sh[1] + sh[2] + sh[3];
}

__global__ void k_sigsum(const float* __restrict__ partial, float* __restrict__ sig) {
    float a = 0.f;
    for (int i = threadIdx.x; i < NEB; i += 512) a += partial[i];
    for (int o = 32; o > 0; o >>= 1) a += __shfl_down(a, o, 64);
    __shared__ float sh[8];
    if ((threadIdx.x & 63) == 0) sh[threadIdx.x >> 6] = a;
    __syncthreads();
    if (threadIdx.x == 0) {
        float s = 0.f;
#pragma unroll
        for (int i = 0; i < 8; ++i) s += sh[i];
        sig[0] = s;
    }
}

// ---------- propagation layer ----------
template <bool PRE>
__global__ __launch_bounds__(256)
void k_gather(const __half* __restrict__ yin, __half* __restrict__ yout,
              const __half* __restrict__ last, const float* __restrict__ norm,
              const int* __restrict__ rowp3, const int* __restrict__ csrB,
              float alpha, float lo, float hi) {
    int t = blockIdx.x * blockDim.x + threadIdx.x;
    if (t >= NN * 6) return;
    int node = t / 6, chb = (t % 6) * 16;
    const char* yb = reinterpret_cast<const char*>(yin) + chb;
    int beg = rowp3[node * NS], end = rowp3[node * NS + NS];
    float4 A0 = make_float4(0, 0, 0, 0), B0 = make_float4(0, 0, 0, 0);
    float4 A1 = make_float4(0, 0, 0, 0), B1 = make_float4(0, 0, 0, 0);
    int k = beg;
    for (; k + 8 <= end; k += 8) {
        int o0 = csrB[k],     o1 = csrB[k + 1], o2 = csrB[k + 2], o3 = csrB[k + 3];
        int o4 = csrB[k + 4], o5 = csrB[k + 5], o6 = csrB[k + 6], o7 = csrB[k + 7];
        uint4 q0 = *reinterpret_cast<const uint4*>(yb + o0);
        uint4 q1 = *reinterpret_cast<const uint4*>(yb + o1);
        uint4 q2 = *reinterpret_cast<const uint4*>(yb + o2);
        uint4 q3 = *reinterpret_cast<const uint4*>(yb + o3);
        uint4 q4 = *reinterpret_cast<const uint4*>(yb + o4);
        uint4 q5 = *reinterpret_cast<const uint4*>(yb + o5);
        uint4 q6 = *reinterpret_cast<const uint4*>(yb + o6);
        uint4 q7 = *reinterpret_cast<const uint4*>(yb + o7);
        h8acc(q0, A0, B0); h8acc(q1, A1, B1);
        h8acc(q2, A0, B0); h8acc(q3, A1, B1);
        h8acc(q4, A0, B0); h8acc(q5, A1, B1);
        h8acc(q6, A0, B0); h8acc(q7, A1, B1);
    }
    for (; k < end; ++k) {
        uint4 q = *reinterpret_cast<const uint4*>(yb + csrB[k]);
        h8acc(q, A0, B0);
    }
    A0.x += A1.x; A0.y += A1.y; A0.z += A1.z; A0.w += A1.w;
    B0.x += B1.x; B0.y += B1.y; B0.z += B1.z; B0.w += B1.w;

    float nd = alpha * norm[node];
    const char* lb = reinterpret_cast<const char*>(last) + (size_t)node * ROWB + chb;
    H8 lt; lt.u = *reinterpret_cast<const uint4*>(lb);
    float2 l0 = __half22float2(lt.h[0]), l1 = __half22float2(lt.h[1]);
    float2 l2 = __half22float2(lt.h[2]), l3 = __half22float2(lt.h[3]);
    float o0 = fminf(fmaxf(fmaf(nd, A0.x, l0.x), lo), hi);
    float o1 = fminf(fmaxf(fmaf(nd, A0.y, l0.y), lo), hi);
    float o2 = fminf(fmaxf(fmaf(nd, A0.z, l1.x), lo), hi);
    float o3 = fminf(fmaxf(fmaf(nd, A0.w, l1.y), lo), hi);
    float o4 = fminf(fmaxf(fmaf(nd, B0.x, l2.x), lo), hi);
    float o5 = fminf(fmaxf(fmaf(nd, B0.y, l2.y), lo), hi);
    float o6 = fminf(fmaxf(fmaf(nd, B0.z, l3.x), lo), hi);
    float o7 = fminf(fmaxf(fmaf(nd, B0.w, l3.y), lo), hi);
    if (PRE) {
        float w = norm[node];
        o0 *= w; o1 *= w; o2 *= w; o3 *= w; o4 *= w; o5 *= w; o6 *= w; o7 *= w;
    }
    H8 ot;
    ot.h[0] = __float22half2_rn(make_float2(o0, o1));
    ot.h[1] = __float22half2_rn(make_float2(o2, o3));
    ot.h[2] = __float22half2_rn(make_float2(o4, o5));
    ot.h[3] = __float22half2_rn(make_float2(o6, o7));
    char* ob = reinterpret_cast<char*>(yout) + (size_t)node * ROWB + chb;
    *reinterpret_cast<uint4*>(ob) = ot.u;
}

// ---------- scale prep ----------
__global__ void k_rowabs(const __half* __restrict__ se, float* __restrict__ rowabs) {
    int v = blockIdx.x * blockDim.x + threadIdx.x;
    if (v >= NN) return;
    const uint4* p = reinterpret_cast<const uint4*>(se + (size_t)v * ROWH);
    float s = 0.f;
#pragma unroll
    for (int k = 0; k < 6; ++k) {
        H8 t; t.u = p[k];
        float2 f0 = __half22float2(t.h[0]), f1 = __half22float2(t.h[1]);
        float2 f2 = __half22float2(t.h[2]), f3 = __half22float2(t.h[3]);
        s += fabsf(f0.x) + fabsf(f0.y) + fabsf(f1.x) + fabsf(f1.y)
           + fabsf(f2.x) + fabsf(f2.y) + fabsf(f3.x) + fabsf(f3.y);
    }
    rowabs[v] = s;
}

__device__ __forceinline__ int cat_at(int i, const int* __restrict__ tr,
                                      const int* __restrict__ va, const int* __restrict__ te) {
    if (i < NTR)        return tr[i];
    if (i < NTR + NVA)  return va[i - NTR];
    return te[i - NTR - NVA];
}

// In-place on A (unscaled smoothed_error in, pre-scaled y_all out).
__global__ void k_phaseD(__half* __restrict__ se_yall, const float* __restrict__ y_soft,
                         const float* __restrict__ rowabs, const float* __restrict__ sig,
                         const int* __restrict__ y_true,
                         const int* __restrict__ tr, const int* __restrict__ va,
                         const int* __restrict__ te, const float* __restrict__ norm,
                         __half* __restrict__ last) {
    int t = blockIdx.x * blockDim.x + threadIdx.x;
    if (t >= NN * 12) return;
    int i = t / 12, ch = (t % 12) * 4;
    int cid = cat_at(i, tr, va, te);
    float4 o;
    if (i < NTR) {
        int yt = y_true[i];
        o.x = (ch + 0 == yt) ? 1.f : 0.f;
        o.y = (ch + 1 == yt) ? 1.f : 0.f;
        o.z = (ch + 2 == yt) ? 1.f : 0.f;
        o.w = (ch + 3 == yt) ? 1.f : 0.f;
    } else {
        float s = (sig[0] * (1.0f / NTR)) / rowabs[i];
        if (s > 1000.0f) s = 1.0f;
        float4 e  = h4f(*reinterpret_cast<const uint2*>(se_yall + (size_t)cid * ROWH + ch));
        float4 ys = *reinterpret_cast<const float4*>(y_soft + (size_t)i * NC + ch);
        o.x = ys.x + s * e.x; if (o.x != o.x) o.x = ys.x;
        o.y = ys.y + s * e.y; if (o.y != o.y) o.y = ys.y;
        o.z = ys.z + s * e.z; if (o.z != o.z) o.z = ys.z;
        o.w = ys.w + s * e.w; if (o.w != o.w) o.w = ys.w;
    }
    float w = norm[cid];
    *reinterpret_cast<uint2*>(se_yall + (size_t)cid * ROWH + ch) =
        f4h(make_float4(o.x * w, o.y * w, o.z * w, o.w * w));
    float la = 1.0f - ALPHA2;
    *reinterpret_cast<uint2*>(last + (size_t)cid * ROWH + ch) =
        f4h(make_float4(la * o.x, la * o.y, la * o.z, la * o.w));
}

// out[i] = yin[cat[i]]  (fp16 padded -> f32 dense)
__global__ void k_outgather(const __half* __restrict__ yin, float* __restrict__ out,
                            const int* __restrict__ tr, const int* __restrict__ va,
                            const int* __restrict__ te) {
    int t = blockIdx.x * blockDim.x + threadIdx.x;
    if (t >= NN * 12) return;
    int i = t / 12, ch = (t % 12) * 4;
    int cid = cat_at(i, tr, va, te);
    float4 v = h4f(*reinterpret_cast<const uint2*>(yin + (size_t)cid * ROWH + ch));
    *reinterpret_cast<float4*>(out + (size_t)i * NC + ch) = v;
}

extern "C" void kernel_launch(void* const* d_in, const int* in_sizes, int n_in,
                              void* d_out, int out_size, void* d_ws, size_t ws_size,
                              hipStream_t stream) {
    const float* y_soft = (const float*)d_in[0];
    const int*   y_true = (const int*)d_in[1];
    const int*   src    = (const int*)d_in[2];
    const int*   dst    = (const int*)d_in[3];
    const int*   tr     = (const int*)d_in[4];
    const int*   va     = (const int*)d_in[5];
    const int*   te     = (const int*)d_in[6];
    float* out = (float*)d_out;

    char* ws = (char*)d_ws;
    size_t off = 0;
    auto alloc = [&](size_t bytes) -> void* {
        void* p = ws + off;
        off += (bytes + 255) & ~(size_t)255;
        return p;
    };
    __half* A      = (__half*)alloc((size_t)NN * ROWH * 2);   // 12.8 MB
    __half* B      = (__half*)alloc((size_t)NN * ROWH * 2);   // 12.8 MB
    __half* last   = (__half*)alloc((size_t)NN * ROWH * 2);   // 12.8 MB
    int*    csr    = (int*)   alloc((size_t)NE * 4);          // 6.4 MB
    int*    staged = (int*)   alloc((size_t)NE * 4);          // 6.4 MB
    int*    deg3   = (int*)   alloc((size_t)N3 * 4);
    int*    rowp3  = (int*)   alloc((size_t)(N3 + 1) * 4);
    int*    bfill  = (int*)   alloc((size_t)NBUK * 4);
    float*  norm   = (float*) alloc((size_t)NN * 4);
    float*  rowabs = (float*) alloc((size_t)NN * 4);
    int*    bsum   = (int*)   alloc((size_t)NB3 * 4);
    float*  partial= (float*) alloc((size_t)NEB * 4);
    float*  sig    = (float*) alloc(256);

    (void)hipMemsetAsync(deg3,  0, (size_t)N3 * 4, stream);
    (void)hipMemsetAsync(bfill, 0, (size_t)NBUK * 4, stream);
    (void)hipMemsetAsync(A,     0, (size_t)NN * ROWH * 2, stream);
    (void)hipMemsetAsync(last,  0, (size_t)NN * ROWH * 2, stream);

    k_count3 <<<NE / 256, 256, 0, stream>>>(src, dst, deg3);
    k_bsum   <<<NB3, 256, 0, stream>>>(deg3, bsum);
    k_bscan  <<<1, 512, 0, stream>>>(bsum);
    k_scatter<<<NB3, 256, 0, stream>>>(deg3, bsum, rowp3);
    k_norm   <<<(NN + 255) / 256, 256, 0, stream>>>(rowp3, norm);
    k_stage  <<<NE / 256, 256, 0, stream>>>(src, dst, rowp3, bfill, staged);
    k_bsort  <<<NBUK, 256, 0, stream>>>(staged, rowp3, csr);
    k_error  <<<NEB, 256, 0, stream>>>(y_soft, y_true, tr, norm, A, last, partial);
    k_sigsum <<<1, 512, 0, stream>>>(partial, sig);

    const int G6  = (NN * 6 + 255) / 256;
    const int G12 = (NN * 12 + 255) / 256;

    // propagation 1: A -> ... -> A (10 layers); last layer unscaled
    __half* cur = A; __half* oth = B;
    for (int l = 0; l < 10; ++l) {
        if (l < 9)
            k_gather<true><<<G6, 256, 0, stream>>>(cur, oth, last, norm, rowp3, csr,
                                                   ALPHA1, -1.f, 1.f);
        else
            k_gather<false><<<G6, 256, 0, stream>>>(cur, oth, last, norm, rowp3, csr,
                                                    ALPHA1, -1.f, 1.f);
        __half* t2 = cur; cur = oth; oth = t2;
    }

    k_rowabs<<<(NN + 255) / 256, 256, 0, stream>>>(A, rowabs);
    // in-place: A := norm .* y_all; last := (1-ALPHA2)*y_all
    k_phaseD<<<G12, 256, 0, stream>>>(A, y_soft, rowabs, sig, y_true,
                                      tr, va, te, norm, last);

    // propagation 2: A -> ... -> A (10 layers); last layer unscaled
    cur = A; oth = B;
    for (int l = 0; l < 10; ++l) {
        if (l < 9)
            k_gather<true><<<G6, 256, 0, stream>>>(cur, oth, last, norm, rowp3, csr,
                                                   ALPHA2, 0.f, 1.f);
        else
            k_gather<false><<<G6, 256, 0, stream>>>(cur, oth, last, norm, rowp3, csr,
                                                    ALPHA2, 0.f, 1.f);
        __half* t2 = cur; cur = oth; oth = t2;
    }

    // d_out[i] = A[cat[i]]
    k_outgather<<<G12, 256, 0, stream>>>(A, out, tr, va, te);
}

// Round 9
// 1055.721 us; speedup vs baseline: 1.2684x; 1.2684x over previous
//
#include <hip/hip_runtime.h>
#include <hip/hip_fp16.h>

// CorrectAndSmooth on MI355X.
// N=100000 nodes, C=48 classes, E=1.6M edges, 10+10 propagation layers.
// R8: revert R7 staging (391-counter atomic contention = 557us).
//     Channel-split propagation: two independent 24-ch arrays, 64B rows,
//     each layer = 2 passes -> per-pass working set 6.4MB (vs 12.8) for
//     higher L2 hit rate; per-edge line traffic 64B/pass.

constexpr int NN  = 100000;
constexpr int NC  = 48;
constexpr int NE  = 1600000;
constexpr int NTR = 10000;
constexpr int NVA = 10000;
constexpr float ALPHA1 = 0.979f;
constexpr float ALPHA2 = 0.756f;
constexpr int RH = 32;             // halfs per half-row (64B, 24 used)
constexpr int RB = 64;             // bytes per half-row

constexpr int NS = 4;                          // src slices
constexpr int SW = (NN + NS - 1) / NS;         // 25000
constexpr int N3 = NN * NS;                    // 400000 cells
constexpr int SCAN_B = 1024;
constexpr int NB3 = (N3 + SCAN_B - 1) / SCAN_B;   // 391
constexpr int NEB = (NTR * 12 + 255) / 256;

union H4 { uint2 u; __half2 h[2]; };

__device__ __forceinline__ float4 h4f(uint2 q) {
    H4 t; t.u = q;
    float2 a = __half22float2(t.h[0]), b = __half22float2(t.h[1]);
    return make_float4(a.x, a.y, b.x, b.y);
}
__device__ __forceinline__ uint2 f4h(float4 v) {
    H4 t;
    t.h[0] = __float22half2_rn(make_float2(v.x, v.y));
    t.h[1] = __float22half2_rn(make_float2(v.z, v.w));
    return t.u;
}

union H8 { uint4 u; __half2 h[4]; };

__device__ __forceinline__ void h8acc(uint4 q, float4& A, float4& B) {
    H8 t; t.u = q;
    float2 f0 = __half22float2(t.h[0]), f1 = __half22float2(t.h[1]);
    float2 f2 = __half22float2(t.h[2]), f3 = __half22float2(t.h[3]);
    A.x += f0.x; A.y += f0.y; A.z += f1.x; A.w += f1.y;
    B.x += f2.x; B.y += f2.y; B.z += f3.x; B.w += f3.y;
}

// ---------- preprocessing ----------

__global__ void k_count3(const int* __restrict__ src, const int* __restrict__ dst,
                         int* __restrict__ deg3) {
    int e = blockIdx.x * blockDim.x + threadIdx.x;
    if (e < NE) {
        int d = dst[e], s = src[e] / SW;
        atomicAdd(&deg3[d * NS + s], 1);
    }
}

__global__ void k_bsum(const int* __restrict__ deg3, int* __restrict__ bsum) {
    int base = blockIdx.x * SCAN_B + threadIdx.x * 4;
    int s = 0;
    if (base + 3 < N3) {
        int4 q = *reinterpret_cast<const int4*>(deg3 + base);
        s = q.x + q.y + q.z + q.w;
    } else {
#pragma unroll
        for (int i = 0; i < 4; ++i) if (base + i < N3) s += deg3[base + i];
    }
    for (int o = 32; o > 0; o >>= 1) s += __shfl_down(s, o, 64);
    __shared__ int sh[4];
    if ((threadIdx.x & 63) == 0) sh[threadIdx.x >> 6] = s;
    __syncthreads();
    if (threadIdx.x == 0) bsum[blockIdx.x] = sh[0] + sh[1] + sh[2] + sh[3];
}

__global__ void k_bscan(int* __restrict__ bsum) {
    __shared__ int sh[512];
    int t = threadIdx.x;
    int v = (t < NB3) ? bsum[t] : 0;
    sh[t] = v;
    __syncthreads();
    for (int o = 1; o < 512; o <<= 1) {
        int u = (t >= o) ? sh[t - o] : 0;
        __syncthreads();
        sh[t] += u;
        __syncthreads();
    }
    if (t < NB3) bsum[t] = sh[t] - v;
}

__global__ void k_scatter(const int* __restrict__ deg3, const int* __restrict__ boff,
                          int* __restrict__ rowp3) {
    int base = blockIdx.x * SCAN_B + threadIdx.x * 4;
    int v0 = 0, v1 = 0, v2 = 0, v3 = 0;
    if (base + 3 < N3) {
        int4 q = *reinterpret_cast<const int4*>(deg3 + base);
        v0 = q.x; v1 = q.y; v2 = q.z; v3 = q.w;
    } else {
        if (base     < N3) v0 = deg3[base];
        if (base + 1 < N3) v1 = deg3[base + 1];
        if (base + 2 < N3) v2 = deg3[base + 2];
        if (base + 3 < N3) v3 = deg3[base + 3];
    }
    int tsum = v0 + v1 + v2 + v3;
    int lane = threadIdx.x & 63, w = threadIdx.x >> 6;
    int inc = tsum;
    for (int o = 1; o < 64; o <<= 1) {
        int u = __shfl_up(inc, o, 64);
        if (lane >= o) inc += u;
    }
    __shared__ int wsum[4];
    if (lane == 63) wsum[w] = inc;
    __syncthreads();
    int woff = 0;
#pragma unroll
    for (int i = 0; i < 4; ++i) if (i < w) woff += wsum[i];
    int ex = boff[blockIdx.x] + woff + inc - tsum;
    if (base     < N3) rowp3[base]     = ex;
    if (base + 1 < N3) rowp3[base + 1] = ex + v0;
    if (base + 2 < N3) rowp3[base + 2] = ex + v0 + v1;
    if (base + 3 < N3) rowp3[base + 3] = ex + v0 + v1 + v2;
    if (blockIdx.x == 0 && threadIdx.x == 0) rowp3[N3] = NE;
}

__global__ void k_norm(const int* __restrict__ rowp3, float* __restrict__ norm) {
    int v = blockIdx.x * blockDim.x + threadIdx.x;
    if (v < NN) {
        int d = rowp3[(v + 1) * NS] - rowp3[v * NS];
        if (d < 1) d = 1;
        norm[v] = rsqrtf((float)d);
    }
}

// csr stores BYTE offset of 64B half-row (src*64)
__global__ void k_fill3(const int* __restrict__ src, const int* __restrict__ dst,
                        const int* __restrict__ rowp3, int* __restrict__ fill3,
                        int* __restrict__ csr) {
    int e = blockIdx.x * blockDim.x + threadIdx.x;
    if (e < NE) {
        int sv = src[e];
        int cell = dst[e] * NS + sv / SW;
        int p = atomicAdd(&fill3[cell], 1);
        csr[rowp3[cell] + p] = sv * RB;
    }
}

// ---------- error build + sigma ----------
// hi holds chs 0..23, lo holds chs 24..47 (both pre-scaled by norm);
// last_hi/lo = (1-ALPHA1)*error (unscaled).
__global__ void k_error(const float* __restrict__ y_soft, const int* __restrict__ y_true,
                        const int* __restrict__ train, const float* __restrict__ norm,
                        __half* __restrict__ Ahi, __half* __restrict__ Alo,
                        __half* __restrict__ Lhi, __half* __restrict__ Llo,
                        float* __restrict__ partial) {
    int t = blockIdx.x * blockDim.x + threadIdx.x;
    float a = 0.f;
    if (t < NTR * 12) {
        int j = t / 12, ch = (t % 12) * 4;
        int yt = y_true[j];
        float4 ys = *reinterpret_cast<const float4*>(y_soft + (size_t)j * NC + ch);
        float e0 = ((ch + 0 == yt) ? 1.f : 0.f) - ys.x;
        float e1 = ((ch + 1 == yt) ? 1.f : 0.f) - ys.y;
        float e2 = ((ch + 2 == yt) ? 1.f : 0.f) - ys.z;
        float e3 = ((ch + 3 == yt) ? 1.f : 0.f) - ys.w;
        int r = train[j];
        float w = norm[r];
        __half* A = (ch < 24) ? Ahi : Alo;
        __half* L = (ch < 24) ? Lhi : Llo;
        int c = (ch < 24) ? ch : ch - 24;
        *reinterpret_cast<uint2*>(A + (size_t)r * RH + c) =
            f4h(make_float4(w * e0, w * e1, w * e2, w * e3));
        float la = 1.0f - ALPHA1;
        *reinterpret_cast<uint2*>(L + (size_t)r * RH + c) =
            f4h(make_float4(la * e0, la * e1, la * e2, la * e3));
        a = fabsf(e0) + fabsf(e1) + fabsf(e2) + fabsf(e3);
    }
    for (int o = 32; o > 0; o >>= 1) a += __shfl_down(a, o, 64);
    __shared__ float sh[4];
    if ((threadIdx.x & 63) == 0) sh[threadIdx.x >> 6] = a;
    __syncthreads();
    if (threadIdx.x == 0) partial[blockIdx.x] = sh[0] + sh[1] + sh[2] + sh[3];
}

__global__ void k_sigsum(const float* __restrict__ partial, float* __restrict__ sig) {
    float a = 0.f;
    for (int i = threadIdx.x; i < NEB; i += 512) a += partial[i];
    for (int o = 32; o > 0; o >>= 1) a += __shfl_down(a, o, 64);
    __shared__ float sh[8];
    if ((threadIdx.x & 63) == 0) sh[threadIdx.x >> 6] = a;
    __syncthreads();
    if (threadIdx.x == 0) {
        float s = 0.f;
#pragma unroll
        for (int i = 0; i < 8; ++i) s += sh[i];
        sig[0] = s;
    }
}

// ---------- propagation half-layer: 3 lanes/node, 16B (8ch) per lane ----------
template <bool PRE>
__global__ __launch_bounds__(256)
void k_gather(const __half* __restrict__ yin, __half* __restrict__ yout,
              const __half* __restrict__ last, const float* __restrict__ norm,
              const int* __restrict__ rowp3, const int* __restrict__ csrB,
              float alpha, float lo, float hi) {
    int t = blockIdx.x * blockDim.x + threadIdx.x;
    if (t >= NN * 3) return;
    int node = t / 3, chb = (t % 3) * 16;
    const char* yb = reinterpret_cast<const char*>(yin) + chb;
    int beg = rowp3[node * NS], end = rowp3[node * NS + NS];
    float4 A0 = make_float4(0, 0, 0, 0), B0 = make_float4(0, 0, 0, 0);
    float4 A1 = make_float4(0, 0, 0, 0), B1 = make_float4(0, 0, 0, 0);
    int k = beg;
    for (; k + 8 <= end; k += 8) {
        int o0 = csrB[k],     o1 = csrB[k + 1], o2 = csrB[k + 2], o3 = csrB[k + 3];
        int o4 = csrB[k + 4], o5 = csrB[k + 5], o6 = csrB[k + 6], o7 = csrB[k + 7];
        uint4 q0 = *reinterpret_cast<const uint4*>(yb + o0);
        uint4 q1 = *reinterpret_cast<const uint4*>(yb + o1);
        uint4 q2 = *reinterpret_cast<const uint4*>(yb + o2);
        uint4 q3 = *reinterpret_cast<const uint4*>(yb + o3);
        uint4 q4 = *reinterpret_cast<const uint4*>(yb + o4);
        uint4 q5 = *reinterpret_cast<const uint4*>(yb + o5);
        uint4 q6 = *reinterpret_cast<const uint4*>(yb + o6);
        uint4 q7 = *reinterpret_cast<const uint4*>(yb + o7);
        h8acc(q0, A0, B0); h8acc(q1, A1, B1);
        h8acc(q2, A0, B0); h8acc(q3, A1, B1);
        h8acc(q4, A0, B0); h8acc(q5, A1, B1);
        h8acc(q6, A0, B0); h8acc(q7, A1, B1);
    }
    for (; k < end; ++k) {
        uint4 q = *reinterpret_cast<const uint4*>(yb + csrB[k]);
        h8acc(q, A0, B0);
    }
    A0.x += A1.x; A0.y += A1.y; A0.z += A1.z; A0.w += A1.w;
    B0.x += B1.x; B0.y += B1.y; B0.z += B1.z; B0.w += B1.w;

    float nd = alpha * norm[node];
    const char* lb = reinterpret_cast<const char*>(last) + (size_t)node * RB + chb;
    H8 lt; lt.u = *reinterpret_cast<const uint4*>(lb);
    float2 l0 = __half22float2(lt.h[0]), l1 = __half22float2(lt.h[1]);
    float2 l2 = __half22float2(lt.h[2]), l3 = __half22float2(lt.h[3]);
    float o0 = fminf(fmaxf(fmaf(nd, A0.x, l0.x), lo), hi);
    float o1 = fminf(fmaxf(fmaf(nd, A0.y, l0.y), lo), hi);
    float o2 = fminf(fmaxf(fmaf(nd, A0.z, l1.x), lo), hi);
    float o3 = fminf(fmaxf(fmaf(nd, A0.w, l1.y), lo), hi);
    float o4 = fminf(fmaxf(fmaf(nd, B0.x, l2.x), lo), hi);
    float o5 = fminf(fmaxf(fmaf(nd, B0.y, l2.y), lo), hi);
    float o6 = fminf(fmaxf(fmaf(nd, B0.z, l3.x), lo), hi);
    float o7 = fminf(fmaxf(fmaf(nd, B0.w, l3.y), lo), hi);
    if (PRE) {
        float w = norm[node];
        o0 *= w; o1 *= w; o2 *= w; o3 *= w; o4 *= w; o5 *= w; o6 *= w; o7 *= w;
    }
    H8 ot;
    ot.h[0] = __float22half2_rn(make_float2(o0, o1));
    ot.h[1] = __float22half2_rn(make_float2(o2, o3));
    ot.h[2] = __float22half2_rn(make_float2(o4, o5));
    ot.h[3] = __float22half2_rn(make_float2(o6, o7));
    char* ob = reinterpret_cast<char*>(yout) + (size_t)node * RB + chb;
    *reinterpret_cast<uint4*>(ob) = ot.u;
}

// ---------- scale prep ----------
__global__ void k_rowabs(const __half* __restrict__ hi, const __half* __restrict__ lo,
                         float* __restrict__ rowabs) {
    int v = blockIdx.x * blockDim.x + threadIdx.x;
    if (v >= NN) return;
    const uint4* ph = reinterpret_cast<const uint4*>(hi + (size_t)v * RH);
    const uint4* pl = reinterpret_cast<const uint4*>(lo + (size_t)v * RH);
    float s = 0.f;
#pragma unroll
    for (int k = 0; k < 3; ++k) {
        H8 a; a.u = ph[k];
        H8 b; b.u = pl[k];
#pragma unroll
        for (int j = 0; j < 4; ++j) {
            float2 fa = __half22float2(a.h[j]), fb = __half22float2(b.h[j]);
            s += fabsf(fa.x) + fabsf(fa.y) + fabsf(fb.x) + fabsf(fb.y);
        }
    }
    rowabs[v] = s;
}

__device__ __forceinline__ int cat_at(int i, const int* __restrict__ tr,
                                      const int* __restrict__ va, const int* __restrict__ te) {
    if (i < NTR)        return tr[i];
    if (i < NTR + NVA)  return va[i - NTR];
    return te[i - NTR - NVA];
}

// In-place on A hi/lo (unscaled smoothed_error in, pre-scaled y_all out).
__global__ void k_phaseD(__half* __restrict__ Ahi, __half* __restrict__ Alo,
                         const float* __restrict__ y_soft,
                         const float* __restrict__ rowabs, const float* __restrict__ sig,
                         const int* __restrict__ y_true,
                         const int* __restrict__ tr, const int* __restrict__ va,
                         const int* __restrict__ te, const float* __restrict__ norm,
                         __half* __restrict__ Lhi, __half* __restrict__ Llo) {
    int t = blockIdx.x * blockDim.x + threadIdx.x;
    if (t >= NN * 12) return;
    int i = t / 12, ch = (t % 12) * 4;
    int cid = cat_at(i, tr, va, te);
    __half* A = (ch < 24) ? Ahi : Alo;
    __half* L = (ch < 24) ? Lhi : Llo;
    int c = (ch < 24) ? ch : ch - 24;
    float4 o;
    if (i < NTR) {
        int yt = y_true[i];
        o.x = (ch + 0 == yt) ? 1.f : 0.f;
        o.y = (ch + 1 == yt) ? 1.f : 0.f;
        o.z = (ch + 2 == yt) ? 1.f : 0.f;
        o.w = (ch + 3 == yt) ? 1.f : 0.f;
    } else {
        float s = (sig[0] * (1.0f / NTR)) / rowabs[i];
        if (s > 1000.0f) s = 1.0f;
        float4 e  = h4f(*reinterpret_cast<const uint2*>(A + (size_t)cid * RH + c));
        float4 ys = *reinterpret_cast<const float4*>(y_soft + (size_t)i * NC + ch);
        o.x = ys.x + s * e.x; if (o.x != o.x) o.x = ys.x;
        o.y = ys.y + s * e.y; if (o.y != o.y) o.y = ys.y;
        o.z = ys.z + s * e.z; if (o.z != o.z) o.z = ys.z;
        o.w = ys.w + s * e.w; if (o.w != o.w) o.w = ys.w;
    }
    float w = norm[cid];
    *reinterpret_cast<uint2*>(A + (size_t)cid * RH + c) =
        f4h(make_float4(o.x * w, o.y * w, o.z * w, o.w * w));
    float la = 1.0f - ALPHA2;
    *reinterpret_cast<uint2*>(L + (size_t)cid * RH + c) =
        f4h(make_float4(la * o.x, la * o.y, la * o.z, la * o.w));
}

// out[i] = yin[cat[i]]
__global__ void k_outgather(const __half* __restrict__ hi, const __half* __restrict__ lo,
                            float* __restrict__ out,
                            const int* __restrict__ tr, const int* __restrict__ va,
                            const int* __restrict__ te) {
    int t = blockIdx.x * blockDim.x + threadIdx.x;
    if (t >= NN * 12) return;
    int i = t / 12, ch = (t % 12) * 4;
    int cid = cat_at(i, tr, va, te);
    const __half* A = (ch < 24) ? hi : lo;
    int c = (ch < 24) ? ch : ch - 24;
    float4 v = h4f(*reinterpret_cast<const uint2*>(A + (size_t)cid * RH + c));
    *reinterpret_cast<float4*>(out + (size_t)i * NC + ch) = v;
}

extern "C" void kernel_launch(void* const* d_in, const int* in_sizes, int n_in,
                              void* d_out, int out_size, void* d_ws, size_t ws_size,
                              hipStream_t stream) {
    const float* y_soft = (const float*)d_in[0];
    const int*   y_true = (const int*)d_in[1];
    const int*   src    = (const int*)d_in[2];
    const int*   dst    = (const int*)d_in[3];
    const int*   tr     = (const int*)d_in[4];
    const int*   va     = (const int*)d_in[5];
    const int*   te     = (const int*)d_in[6];
    float* out = (float*)d_out;

    char* ws = (char*)d_ws;
    size_t off = 0;
    auto alloc = [&](size_t bytes) -> void* {
        void* p = ws + off;
        off += (bytes + 255) & ~(size_t)255;
        return p;
    };
    __half* Ahi = (__half*)alloc((size_t)NN * RH * 2);   // 6.4 MB each
    __half* Alo = (__half*)alloc((size_t)NN * RH * 2);
    __half* Bhi = (__half*)alloc((size_t)NN * RH * 2);
    __half* Blo = (__half*)alloc((size_t)NN * RH * 2);
    __half* Lhi = (__half*)alloc((size_t)NN * RH * 2);
    __half* Llo = (__half*)alloc((size_t)NN * RH * 2);
    int*    csr    = (int*)   alloc((size_t)NE * 4);     // 6.4 MB
    int*    deg3   = (int*)   alloc((size_t)N3 * 4);
    int*    fill3  = (int*)   alloc((size_t)N3 * 4);
    int*    rowp3  = (int*)   alloc((size_t)(N3 + 1) * 4);
    float*  norm   = (float*) alloc((size_t)NN * 4);
    float*  rowabs = (float*) alloc((size_t)NN * 4);
    int*    bsum   = (int*)   alloc((size_t)NB3 * 4);
    float*  partial= (float*) alloc((size_t)NEB * 4);
    float*  sig    = (float*) alloc(256);

    (void)hipMemsetAsync(deg3,  0, (size_t)N3 * 4, stream);
    (void)hipMemsetAsync(fill3, 0, (size_t)N3 * 4, stream);
    (void)hipMemsetAsync(Ahi,   0, (size_t)NN * RH * 2, stream);
    (void)hipMemsetAsync(Alo,   0, (size_t)NN * RH * 2, stream);
    (void)hipMemsetAsync(Lhi,   0, (size_t)NN * RH * 2, stream);
    (void)hipMemsetAsync(Llo,   0, (size_t)NN * RH * 2, stream);

    k_count3 <<<NE / 256, 256, 0, stream>>>(src, dst, deg3);
    k_bsum   <<<NB3, 256, 0, stream>>>(deg3, bsum);
    k_bscan  <<<1, 512, 0, stream>>>(bsum);
    k_scatter<<<NB3, 256, 0, stream>>>(deg3, bsum, rowp3);
    k_norm   <<<(NN + 255) / 256, 256, 0, stream>>>(rowp3, norm);
    k_fill3  <<<NE / 256, 256, 0, stream>>>(src, dst, rowp3, fill3, csr);
    k_error  <<<NEB, 256, 0, stream>>>(y_soft, y_true, tr, norm,
                                       Ahi, Alo, Lhi, Llo, partial);
    k_sigsum <<<1, 512, 0, stream>>>(partial, sig);

    const int G3  = (NN * 3 + 255) / 256;
    const int G12 = (NN * 12 + 255) / 256;

    // propagation 1: 10 layers x {hi, lo}; last layer unscaled. Ends in Ahi/Alo.
    __half *ch_ = Ahi, *oh = Bhi, *cl = Alo, *ol = Blo;
    for (int l = 0; l < 10; ++l) {
        if (l < 9) {
            k_gather<true><<<G3, 256, 0, stream>>>(ch_, oh, Lhi, norm, rowp3, csr,
                                                   ALPHA1, -1.f, 1.f);
            k_gather<true><<<G3, 256, 0, stream>>>(cl, ol, Llo, norm, rowp3, csr,
                                                   ALPHA1, -1.f, 1.f);
        } else {
            k_gather<false><<<G3, 256, 0, stream>>>(ch_, oh, Lhi, norm, rowp3, csr,
                                                    ALPHA1, -1.f, 1.f);
            k_gather<false><<<G3, 256, 0, stream>>>(cl, ol, Llo, norm, rowp3, csr,
                                                    ALPHA1, -1.f, 1.f);
        }
        __half* t2 = ch_; ch_ = oh; oh = t2;
        t2 = cl; cl = ol; ol = t2;
    }

    k_rowabs<<<(NN + 255) / 256, 256, 0, stream>>>(Ahi, Alo, rowabs);
    k_phaseD<<<G12, 256, 0, stream>>>(Ahi, Alo, y_soft, rowabs, sig, y_true,
                                      tr, va, te, norm, Lhi, Llo);

    // propagation 2: 10 layers x {hi, lo}; last layer unscaled. Ends in Ahi/Alo.
    ch_ = Ahi; oh = Bhi; cl = Alo; ol = Blo;
    for (int l = 0; l < 10; ++l) {
        if (l < 9) {
            k_gather<true><<<G3, 256, 0, stream>>>(ch_, oh, Lhi, norm, rowp3, csr,
                                                   ALPHA2, 0.f, 1.f);
            k_gather<true><<<G3, 256, 0, stream>>>(cl, ol, Llo, norm, rowp3, csr,
                                                   ALPHA2, 0.f, 1.f);
        } else {
            k_gather<false><<<G3, 256, 0, stream>>>(ch_, oh, Lhi, norm, rowp3, csr,
                                                    ALPHA2, 0.f, 1.f);
            k_gather<false><<<G3, 256, 0, stream>>>(cl, ol, Llo, norm, rowp3, csr,
                                                    ALPHA2, 0.f, 1.f);
        }
        __half* t2 = ch_; ch_ = oh; oh = t2;
        t2 = cl; cl = ol; ol = t2;
    }

    // d_out[i] = A[cat[i]]
    k_outgather<<<G12, 256, 0, stream>>>(Ahi, Alo, out, tr, va, te);
}

// Round 10
// 901.501 us; speedup vs baseline: 1.4853x; 1.1711x over previous
//
#include <hip/hip_runtime.h>
#include <hip/hip_fp16.h>

// CorrectAndSmooth on MI355X.
// N=100000 nodes, C=48 classes, E=1.6M edges, 10+10 propagation layers.
// R9: revert R8 channel split (doubled line requests: request-rate bound).
//     Back to R6 structure (128B padded rows, 6 lanes/node). NEW: per-XCD
//     rotated slice order in k_gather (s_getreg XCC_ID) so each XCD's
//     concurrent reads stay in one L2-resident 3.2MB slice window.

constexpr int NN  = 100000;
constexpr int NC  = 48;
constexpr int NE  = 1600000;
constexpr int NTR = 10000;
constexpr int NVA = 10000;
constexpr float ALPHA1 = 0.979f;
constexpr float ALPHA2 = 0.756f;
constexpr int ROWH = 64;           // halfs per padded row (128B)
constexpr int ROWB = 128;          // bytes per padded row

constexpr int NS = 4;                          // src slices (3.2MB fp16/slice)
constexpr int SW = (NN + NS - 1) / NS;         // 25000
constexpr int N3 = NN * NS;                    // 400000 cells
constexpr int SCAN_B = 1024;
constexpr int NB3 = (N3 + SCAN_B - 1) / SCAN_B;   // 391
constexpr int NEB = (NTR * 12 + 255) / 256;

union H4 { uint2 u; __half2 h[2]; };

__device__ __forceinline__ float4 h4f(uint2 q) {
    H4 t; t.u = q;
    float2 a = __half22float2(t.h[0]), b = __half22float2(t.h[1]);
    return make_float4(a.x, a.y, b.x, b.y);
}
__device__ __forceinline__ uint2 f4h(float4 v) {
    H4 t;
    t.h[0] = __float22half2_rn(make_float2(v.x, v.y));
    t.h[1] = __float22half2_rn(make_float2(v.z, v.w));
    return t.u;
}

union H8 { uint4 u; __half2 h[4]; };

__device__ __forceinline__ void h8acc(uint4 q, float4& A, float4& B) {
    H8 t; t.u = q;
    float2 f0 = __half22float2(t.h[0]), f1 = __half22float2(t.h[1]);
    float2 f2 = __half22float2(t.h[2]), f3 = __half22float2(t.h[3]);
    A.x += f0.x; A.y += f0.y; A.z += f1.x; A.w += f1.y;
    B.x += f2.x; B.y += f2.y; B.z += f3.x; B.w += f3.y;
}

// ---------- preprocessing ----------

__global__ void k_count3(const int* __restrict__ src, const int* __restrict__ dst,
                         int* __restrict__ deg3) {
    int e = blockIdx.x * blockDim.x + threadIdx.x;
    if (e < NE) {
        int d = dst[e], s = src[e] / SW;
        atomicAdd(&deg3[d * NS + s], 1);
    }
}

__global__ void k_bsum(const int* __restrict__ deg3, int* __restrict__ bsum) {
    int base = blockIdx.x * SCAN_B + threadIdx.x * 4;
    int s = 0;
    if (base + 3 < N3) {
        int4 q = *reinterpret_cast<const int4*>(deg3 + base);
        s = q.x + q.y + q.z + q.w;
    } else {
#pragma unroll
        for (int i = 0; i < 4; ++i) if (base + i < N3) s += deg3[base + i];
    }
    for (int o = 32; o > 0; o >>= 1) s += __shfl_down(s, o, 64);
    __shared__ int sh[4];
    if ((threadIdx.x & 63) == 0) sh[threadIdx.x >> 6] = s;
    __syncthreads();
    if (threadIdx.x == 0) bsum[blockIdx.x] = sh[0] + sh[1] + sh[2] + sh[3];
}

__global__ void k_bscan(int* __restrict__ bsum) {
    __shared__ int sh[512];
    int t = threadIdx.x;
    int v = (t < NB3) ? bsum[t] : 0;
    sh[t] = v;
    __syncthreads();
    for (int o = 1; o < 512; o <<= 1) {
        int u = (t >= o) ? sh[t - o] : 0;
        __syncthreads();
        sh[t] += u;
        __syncthreads();
    }
    if (t < NB3) bsum[t] = sh[t] - v;
}

__global__ void k_scatter(const int* __restrict__ deg3, const int* __restrict__ boff,
                          int* __restrict__ rowp3) {
    int base = blockIdx.x * SCAN_B + threadIdx.x * 4;
    int v0 = 0, v1 = 0, v2 = 0, v3 = 0;
    if (base + 3 < N3) {
        int4 q = *reinterpret_cast<const int4*>(deg3 + base);
        v0 = q.x; v1 = q.y; v2 = q.z; v3 = q.w;
    } else {
        if (base     < N3) v0 = deg3[base];
        if (base + 1 < N3) v1 = deg3[base + 1];
        if (base + 2 < N3) v2 = deg3[base + 2];
        if (base + 3 < N3) v3 = deg3[base + 3];
    }
    int tsum = v0 + v1 + v2 + v3;
    int lane = threadIdx.x & 63, w = threadIdx.x >> 6;
    int inc = tsum;
    for (int o = 1; o < 64; o <<= 1) {
        int u = __shfl_up(inc, o, 64);
        if (lane >= o) inc += u;
    }
    __shared__ int wsum[4];
    if (lane == 63) wsum[w] = inc;
    __syncthreads();
    int woff = 0;
#pragma unroll
    for (int i = 0; i < 4; ++i) if (i < w) woff += wsum[i];
    int ex = boff[blockIdx.x] + woff + inc - tsum;
    if (base     < N3) rowp3[base]     = ex;
    if (base + 1 < N3) rowp3[base + 1] = ex + v0;
    if (base + 2 < N3) rowp3[base + 2] = ex + v0 + v1;
    if (base + 3 < N3) rowp3[base + 3] = ex + v0 + v1 + v2;
    if (blockIdx.x == 0 && threadIdx.x == 0) rowp3[N3] = NE;
}

__global__ void k_norm(const int* __restrict__ rowp3, float* __restrict__ norm) {
    int v = blockIdx.x * blockDim.x + threadIdx.x;
    if (v < NN) {
        int d = rowp3[(v + 1) * NS] - rowp3[v * NS];
        if (d < 1) d = 1;
        norm[v] = rsqrtf((float)d);
    }
}

// csr stores BYTE offset of padded src row (src*128)
__global__ void k_fill3(const int* __restrict__ src, const int* __restrict__ dst,
                        const int* __restrict__ rowp3, int* __restrict__ fill3,
                        int* __restrict__ csr) {
    int e = blockIdx.x * blockDim.x + threadIdx.x;
    if (e < NE) {
        int sv = src[e];
        int cell = dst[e] * NS + sv / SW;
        int p = atomicAdd(&fill3[cell], 1);
        csr[rowp3[cell] + p] = sv * ROWB;
    }
}

// ---------- error build + sigma (two-stage, no global atomics) ----------
__global__ void k_error(const float* __restrict__ y_soft, const int* __restrict__ y_true,
                        const int* __restrict__ train, const float* __restrict__ norm,
                        __half* __restrict__ A, __half* __restrict__ last,
                        float* __restrict__ partial) {
    int t = blockIdx.x * blockDim.x + threadIdx.x;
    float a = 0.f;
    if (t < NTR * 12) {
        int j = t / 12, ch = (t % 12) * 4;
        int yt = y_true[j];
        float4 ys = *reinterpret_cast<const float4*>(y_soft + (size_t)j * NC + ch);
        float e0 = ((ch + 0 == yt) ? 1.f : 0.f) - ys.x;
        float e1 = ((ch + 1 == yt) ? 1.f : 0.f) - ys.y;
        float e2 = ((ch + 2 == yt) ? 1.f : 0.f) - ys.z;
        float e3 = ((ch + 3 == yt) ? 1.f : 0.f) - ys.w;
        int r = train[j];
        float w = norm[r];
        *reinterpret_cast<uint2*>(A + (size_t)r * ROWH + ch) =
            f4h(make_float4(w * e0, w * e1, w * e2, w * e3));
        float la = 1.0f - ALPHA1;
        *reinterpret_cast<uint2*>(last + (size_t)r * ROWH + ch) =
            f4h(make_float4(la * e0, la * e1, la * e2, la * e3));
        a = fabsf(e0) + fabsf(e1) + fabsf(e2) + fabsf(e3);
    }
    for (int o = 32; o > 0; o >>= 1) a += __shfl_down(a, o, 64);
    __shared__ float sh[4];
    if ((threadIdx.x & 63) == 0) sh[threadIdx.x >> 6] = a;
    __syncthreads();
    if (threadIdx.x == 0) partial[blockIdx.x] = sh[0] + sh[1] + sh[2] + sh[3];
}

__global__ void k_sigsum(const float* __restrict__ partial, float* __restrict__ sig) {
    float a = 0.f;
    for (int i = threadIdx.x; i < NEB; i += 512) a += partial[i];
    for (int o = 32; o > 0; o >>= 1) a += __shfl_down(a, o, 64);
    __shared__ float sh[8];
    if ((threadIdx.x & 63) == 0) sh[threadIdx.x >> 6] = a;
    __syncthreads();
    if (threadIdx.x == 0) {
        float s = 0.f;
#pragma unroll
        for (int i = 0; i < 8; ++i) s += sh[i];
        sig[0] = s;
    }
}

// ---------- propagation layer ----------
// 6 lanes/node, 16B/lane. Slices walked in XCD-rotated order so each XCD's
// concurrent random reads concentrate in one 3.2MB (L2-resident) window.
template <bool PRE>
__global__ __launch_bounds__(256)
void k_gather(const __half* __restrict__ yin, __half* __restrict__ yout,
              const __half* __restrict__ last, const float* __restrict__ norm,
              const int* __restrict__ rowp3, const int* __restrict__ csrB,
              float alpha, float lo, float hi) {
    int t = blockIdx.x * blockDim.x + threadIdx.x;
    if (t >= NN * 6) return;
    int node = t / 6, chb = (t % 6) * 16;
    const char* yb = reinterpret_cast<const char*>(yin) + chb;

    int xcc;
    asm("s_getreg_b32 %0, hwreg(HW_REG_XCC_ID)" : "=s"(xcc));
    int s0 = xcc & (NS - 1);

    float4 A0 = make_float4(0, 0, 0, 0), B0 = make_float4(0, 0, 0, 0);
    float4 A1 = make_float4(0, 0, 0, 0), B1 = make_float4(0, 0, 0, 0);
#pragma unroll
    for (int si = 0; si < NS; ++si) {
        int s = (s0 + si) & (NS - 1);
        int k  = rowp3[node * NS + s];
        int ke = rowp3[node * NS + s + 1];
        for (; k + 4 <= ke; k += 4) {
            int o0 = csrB[k], o1 = csrB[k + 1], o2 = csrB[k + 2], o3 = csrB[k + 3];
            uint4 q0 = *reinterpret_cast<const uint4*>(yb + o0);
            uint4 q1 = *reinterpret_cast<const uint4*>(yb + o1);
            uint4 q2 = *reinterpret_cast<const uint4*>(yb + o2);
            uint4 q3 = *reinterpret_cast<const uint4*>(yb + o3);
            h8acc(q0, A0, B0); h8acc(q1, A1, B1);
            h8acc(q2, A0, B0); h8acc(q3, A1, B1);
        }
        for (; k < ke; ++k) {
            uint4 q = *reinterpret_cast<const uint4*>(yb + csrB[k]);
            h8acc(q, A0, B0);
        }
    }
    A0.x += A1.x; A0.y += A1.y; A0.z += A1.z; A0.w += A1.w;
    B0.x += B1.x; B0.y += B1.y; B0.z += B1.z; B0.w += B1.w;

    float nd = alpha * norm[node];
    const char* lb = reinterpret_cast<const char*>(last) + (size_t)node * ROWB + chb;
    H8 lt; lt.u = *reinterpret_cast<const uint4*>(lb);
    float2 l0 = __half22float2(lt.h[0]), l1 = __half22float2(lt.h[1]);
    float2 l2 = __half22float2(lt.h[2]), l3 = __half22float2(lt.h[3]);
    float o0 = fminf(fmaxf(fmaf(nd, A0.x, l0.x), lo), hi);
    float o1 = fminf(fmaxf(fmaf(nd, A0.y, l0.y), lo), hi);
    float o2 = fminf(fmaxf(fmaf(nd, A0.z, l1.x), lo), hi);
    float o3 = fminf(fmaxf(fmaf(nd, A0.w, l1.y), lo), hi);
    float o4 = fminf(fmaxf(fmaf(nd, B0.x, l2.x), lo), hi);
    float o5 = fminf(fmaxf(fmaf(nd, B0.y, l2.y), lo), hi);
    float o6 = fminf(fmaxf(fmaf(nd, B0.z, l3.x), lo), hi);
    float o7 = fminf(fmaxf(fmaf(nd, B0.w, l3.y), lo), hi);
    if (PRE) {
        float w = norm[node];
        o0 *= w; o1 *= w; o2 *= w; o3 *= w; o4 *= w; o5 *= w; o6 *= w; o7 *= w;
    }
    H8 ot;
    ot.h[0] = __float22half2_rn(make_float2(o0, o1));
    ot.h[1] = __float22half2_rn(make_float2(o2, o3));
    ot.h[2] = __float22half2_rn(make_float2(o4, o5));
    ot.h[3] = __float22half2_rn(make_float2(o6, o7));
    char* ob = reinterpret_cast<char*>(yout) + (size_t)node * ROWB + chb;
    *reinterpret_cast<uint4*>(ob) = ot.u;
}

// ---------- scale prep ----------
__global__ void k_rowabs(const __half* __restrict__ se, float* __restrict__ rowabs) {
    int v = blockIdx.x * blockDim.x + threadIdx.x;
    if (v >= NN) return;
    const uint4* p = reinterpret_cast<const uint4*>(se + (size_t)v * ROWH);
    float s = 0.f;
#pragma unroll
    for (int k = 0; k < 6; ++k) {
        H8 t; t.u = p[k];
        float2 f0 = __half22float2(t.h[0]), f1 = __half22float2(t.h[1]);
        float2 f2 = __half22float2(t.h[2]), f3 = __half22float2(t.h[3]);
        s += fabsf(f0.x) + fabsf(f0.y) + fabsf(f1.x) + fabsf(f1.y)
           + fabsf(f2.x) + fabsf(f2.y) + fabsf(f3.x) + fabsf(f3.y);
    }
    rowabs[v] = s;
}

__device__ __forceinline__ int cat_at(int i, const int* __restrict__ tr,
                                      const int* __restrict__ va, const int* __restrict__ te) {
    if (i < NTR)        return tr[i];
    if (i < NTR + NVA)  return va[i - NTR];
    return te[i - NTR - NVA];
}

// In-place on A (unscaled smoothed_error in, pre-scaled y_all out).
__global__ void k_phaseD(__half* __restrict__ se_yall, const float* __restrict__ y_soft,
                         const float* __restrict__ rowabs, const float* __restrict__ sig,
                         const int* __restrict__ y_true,
                         const int* __restrict__ tr, const int* __restrict__ va,
                         const int* __restrict__ te, const float* __restrict__ norm,
                         __half* __restrict__ last) {
    int t = blockIdx.x * blockDim.x + threadIdx.x;
    if (t >= NN * 12) return;
    int i = t / 12, ch = (t % 12) * 4;
    int cid = cat_at(i, tr, va, te);
    float4 o;
    if (i < NTR) {
        int yt = y_true[i];
        o.x = (ch + 0 == yt) ? 1.f : 0.f;
        o.y = (ch + 1 == yt) ? 1.f : 0.f;
        o.z = (ch + 2 == yt) ? 1.f : 0.f;
        o.w = (ch + 3 == yt) ? 1.f : 0.f;
    } else {
        float s = (sig[0] * (1.0f / NTR)) / rowabs[i];
        if (s > 1000.0f) s = 1.0f;
        float4 e  = h4f(*reinterpret_cast<const uint2*>(se_yall + (size_t)cid * ROWH + ch));
        float4 ys = *reinterpret_cast<const float4*>(y_soft + (size_t)i * NC + ch);
        o.x = ys.x + s * e.x; if (o.x != o.x) o.x = ys.x;
        o.y = ys.y + s * e.y; if (o.y != o.y) o.y = ys.y;
        o.z = ys.z + s * e.z; if (o.z != o.z) o.z = ys.z;
        o.w = ys.w + s * e.w; if (o.w != o.w) o.w = ys.w;
    }
    float w = norm[cid];
    *reinterpret_cast<uint2*>(se_yall + (size_t)cid * ROWH + ch) =
        f4h(make_float4(o.x * w, o.y * w, o.z * w, o.w * w));
    float la = 1.0f - ALPHA2;
    *reinterpret_cast<uint2*>(last + (size_t)cid * ROWH + ch) =
        f4h(make_float4(la * o.x, la * o.y, la * o.z, la * o.w));
}

// out[i] = yin[cat[i]]  (fp16 padded -> f32 dense)
__global__ void k_outgather(const __half* __restrict__ yin, float* __restrict__ out,
                            const int* __restrict__ tr, const int* __restrict__ va,
                            const int* __restrict__ te) {
    int t = blockIdx.x * blockDim.x + threadIdx.x;
    if (t >= NN * 12) return;
    int i = t / 12, ch = (t % 12) * 4;
    int cid = cat_at(i, tr, va, te);
    float4 v = h4f(*reinterpret_cast<const uint2*>(yin + (size_t)cid * ROWH + ch));
    *reinterpret_cast<float4*>(out + (size_t)i * NC + ch) = v;
}

extern "C" void kernel_launch(void* const* d_in, const int* in_sizes, int n_in,
                              void* d_out, int out_size, void* d_ws, size_t ws_size,
                              hipStream_t stream) {
    const float* y_soft = (const float*)d_in[0];
    const int*   y_true = (const int*)d_in[1];
    const int*   src    = (const int*)d_in[2];
    const int*   dst    = (const int*)d_in[3];
    const int*   tr     = (const int*)d_in[4];
    const int*   va     = (const int*)d_in[5];
    const int*   te     = (const int*)d_in[6];
    float* out = (float*)d_out;

    char* ws = (char*)d_ws;
    size_t off = 0;
    auto alloc = [&](size_t bytes) -> void* {
        void* p = ws + off;
        off += (bytes + 255) & ~(size_t)255;
        return p;
    };
    __half* A      = (__half*)alloc((size_t)NN * ROWH * 2);   // 12.8 MB
    __half* B      = (__half*)alloc((size_t)NN * ROWH * 2);   // 12.8 MB
    __half* last   = (__half*)alloc((size_t)NN * ROWH * 2);   // 12.8 MB
    int*    csr    = (int*)   alloc((size_t)NE * 4);          // 6.4 MB
    int*    deg3   = (int*)   alloc((size_t)N3 * 4);
    int*    fill3  = (int*)   alloc((size_t)N3 * 4);
    int*    rowp3  = (int*)   alloc((size_t)(N3 + 1) * 4);
    float*  norm   = (float*) alloc((size_t)NN * 4);
    float*  rowabs = (float*) alloc((size_t)NN * 4);
    int*    bsum   = (int*)   alloc((size_t)NB3 * 4);
    float*  partial= (float*) alloc((size_t)NEB * 4);
    float*  sig    = (float*) alloc(256);

    (void)hipMemsetAsync(deg3,  0, (size_t)N3 * 4, stream);
    (void)hipMemsetAsync(fill3, 0, (size_t)N3 * 4, stream);
    (void)hipMemsetAsync(A,     0, (size_t)NN * ROWH * 2, stream);
    (void)hipMemsetAsync(last,  0, (size_t)NN * ROWH * 2, stream);

    k_count3 <<<NE / 256, 256, 0, stream>>>(src, dst, deg3);
    k_bsum   <<<NB3, 256, 0, stream>>>(deg3, bsum);
    k_bscan  <<<1, 512, 0, stream>>>(bsum);
    k_scatter<<<NB3, 256, 0, stream>>>(deg3, bsum, rowp3);
    k_norm   <<<(NN + 255) / 256, 256, 0, stream>>>(rowp3, norm);
    k_fill3  <<<NE / 256, 256, 0, stream>>>(src, dst, rowp3, fill3, csr);
    k_error  <<<NEB, 256, 0, stream>>>(y_soft, y_true, tr, norm, A, last, partial);
    k_sigsum <<<1, 512, 0, stream>>>(partial, sig);

    const int G6  = (NN * 6 + 255) / 256;
    const int G12 = (NN * 12 + 255) / 256;

    // propagation 1: A -> ... -> A (10 layers); last layer unscaled
    __half* cur = A; __half* oth = B;
    for (int l = 0; l < 10; ++l) {
        if (l < 9)
            k_gather<true><<<G6, 256, 0, stream>>>(cur, oth, last, norm, rowp3, csr,
                                                   ALPHA1, -1.f, 1.f);
        else
            k_gather<false><<<G6, 256, 0, stream>>>(cur, oth, last, norm, rowp3, csr,
                                                    ALPHA1, -1.f, 1.f);
        __half* t2 = cur; cur = oth; oth = t2;
    }

    k_rowabs<<<(NN + 255) / 256, 256, 0, stream>>>(A, rowabs);
    // in-place: A := norm .* y_all; last := (1-ALPHA2)*y_all
    k_phaseD<<<G12, 256, 0, stream>>>(A, y_soft, rowabs, sig, y_true,
                                      tr, va, te, norm, last);

    // propagation 2: A -> ... -> A (10 layers); last layer unscaled
    cur = A; oth = B;
    for (int l = 0; l < 10; ++l) {
        if (l < 9)
            k_gather<true><<<G6, 256, 0, stream>>>(cur, oth, last, norm, rowp3, csr,
                                                   ALPHA2, 0.f, 1.f);
        else
            k_gather<false><<<G6, 256, 0, stream>>>(cur, oth, last, norm, rowp3, csr,
                                                    ALPHA2, 0.f, 1.f);
        __half* t2 = cur; cur = oth; oth = t2;
    }

    // d_out[i] = A[cat[i]]
    k_outgather<<<G12, 256, 0, stream>>>(A, out, tr, va, te);
}

// Round 11
// 808.834 us; speedup vs baseline: 1.6555x; 1.1146x over previous
//
#include <hip/hip_runtime.h>
#include <hip/hip_fp16.h>

// CorrectAndSmooth on MI355X.
// N=100000 nodes, C=48 classes, E=1.6M edges, 10+10 propagation layers.
// R10: revert R9 slice rotation (regressed +43us); drop slicing entirely
//      (plain dst CSR). CSR build = two-pass with LDS-aggregated bucket
//      reservation (391 global atomics/block, not per-edge) + per-bucket
//      LDS counting sort -> sequential csr writes. Gather = R6 form.

constexpr int NN  = 100000;
constexpr int NC  = 48;
constexpr int NE  = 1600000;
constexpr int NTR = 10000;
constexpr int NVA = 10000;
constexpr float ALPHA1 = 0.979f;
constexpr float ALPHA2 = 0.756f;
constexpr int ROWH = 64;           // halfs per padded row (128B)
constexpr int ROWB = 128;          // bytes per padded row

constexpr int SCAN_B = 1024;
constexpr int NB  = (NN + SCAN_B - 1) / SCAN_B;   // 98 scan blocks
constexpr int NBUK = (NN + 255) / 256;            // 391 dst buckets
constexpr int EPB  = 8192;                        // edges per stage block
constexpr int NSB  = (NE + EPB - 1) / EPB;        // 196 stage blocks
constexpr int NEB  = (NTR * 12 + 255) / 256;      // k_error blocks

union H4 { uint2 u; __half2 h[2]; };

__device__ __forceinline__ float4 h4f(uint2 q) {
    H4 t; t.u = q;
    float2 a = __half22float2(t.h[0]), b = __half22float2(t.h[1]);
    return make_float4(a.x, a.y, b.x, b.y);
}
__device__ __forceinline__ uint2 f4h(float4 v) {
    H4 t;
    t.h[0] = __float22half2_rn(make_float2(v.x, v.y));
    t.h[1] = __float22half2_rn(make_float2(v.z, v.w));
    return t.u;
}

union H8 { uint4 u; __half2 h[4]; };

__device__ __forceinline__ void h8acc(uint4 q, float4& A, float4& B) {
    H8 t; t.u = q;
    float2 f0 = __half22float2(t.h[0]), f1 = __half22float2(t.h[1]);
    float2 f2 = __half22float2(t.h[2]), f3 = __half22float2(t.h[3]);
    A.x += f0.x; A.y += f0.y; A.z += f1.x; A.w += f1.y;
    B.x += f2.x; B.y += f2.y; B.z += f3.x; B.w += f3.y;
}

// ---------- preprocessing ----------

__global__ void k_count(const int* __restrict__ dst, int* __restrict__ deg) {
    int e = blockIdx.x * blockDim.x + threadIdx.x;
    if (e < NE) atomicAdd(&deg[dst[e]], 1);
}

__global__ void k_bsum(const int* __restrict__ deg, int* __restrict__ bsum) {
    int base = blockIdx.x * SCAN_B + threadIdx.x * 4;
    int s = 0;
    if (base + 3 < NN) {
        int4 q = *reinterpret_cast<const int4*>(deg + base);
        s = q.x + q.y + q.z + q.w;
    } else {
#pragma unroll
        for (int i = 0; i < 4; ++i) if (base + i < NN) s += deg[base + i];
    }
    for (int o = 32; o > 0; o >>= 1) s += __shfl_down(s, o, 64);
    __shared__ int sh[4];
    if ((threadIdx.x & 63) == 0) sh[threadIdx.x >> 6] = s;
    __syncthreads();
    if (threadIdx.x == 0) bsum[blockIdx.x] = sh[0] + sh[1] + sh[2] + sh[3];
}

__global__ void k_bscan(int* __restrict__ bsum) {
    __shared__ int sh[128];
    int t = threadIdx.x;
    int v = (t < NB) ? bsum[t] : 0;
    sh[t] = v;
    __syncthreads();
    for (int o = 1; o < 128; o <<= 1) {
        int u = (t >= o) ? sh[t - o] : 0;
        __syncthreads();
        sh[t] += u;
        __syncthreads();
    }
    if (t < NB) bsum[t] = sh[t] - v;
}

__global__ void k_scatter(const int* __restrict__ deg, const int* __restrict__ boff,
                          int* __restrict__ rowp) {
    int base = blockIdx.x * SCAN_B + threadIdx.x * 4;
    int v0 = 0, v1 = 0, v2 = 0, v3 = 0;
    if (base + 3 < NN) {
        int4 q = *reinterpret_cast<const int4*>(deg + base);
        v0 = q.x; v1 = q.y; v2 = q.z; v3 = q.w;
    } else {
        if (base     < NN) v0 = deg[base];
        if (base + 1 < NN) v1 = deg[base + 1];
        if (base + 2 < NN) v2 = deg[base + 2];
        if (base + 3 < NN) v3 = deg[base + 3];
    }
    int tsum = v0 + v1 + v2 + v3;
    int lane = threadIdx.x & 63, w = threadIdx.x >> 6;
    int inc = tsum;
    for (int o = 1; o < 64; o <<= 1) {
        int u = __shfl_up(inc, o, 64);
        if (lane >= o) inc += u;
    }
    __shared__ int wsum[4];
    if (lane == 63) wsum[w] = inc;
    __syncthreads();
    int woff = 0;
#pragma unroll
    for (int i = 0; i < 4; ++i) if (i < w) woff += wsum[i];
    int ex = boff[blockIdx.x] + woff + inc - tsum;
    if (base     < NN) rowp[base]     = ex;
    if (base + 1 < NN) rowp[base + 1] = ex + v0;
    if (base + 2 < NN) rowp[base + 2] = ex + v0 + v1;
    if (base + 3 < NN) rowp[base + 3] = ex + v0 + v1 + v2;
    if (blockIdx.x == 0 && threadIdx.x == 0) rowp[NN] = NE;
}

__global__ void k_norm(const int* __restrict__ rowp, float* __restrict__ norm) {
    int v = blockIdx.x * blockDim.x + threadIdx.x;
    if (v < NN) {
        int d = rowp[v + 1] - rowp[v];
        if (d < 1) d = 1;
        norm[v] = rsqrtf((float)d);
    }
}

// Pass A: stage edges into per-bucket (dst>>8) regions of `staged`.
// Per block: LDS histogram -> ONE global atomic per bucket to reserve a
// range -> contiguous-run writes. word = src | (dst&255)<<17.
__global__ __launch_bounds__(1024)
void k_stage2(const int* __restrict__ src, const int* __restrict__ dst,
              const int* __restrict__ rowp, int* __restrict__ bfill,
              int* __restrict__ staged) {
    __shared__ int hist[NBUK];
    __shared__ int gb[NBUK];
    __shared__ int ofs[NBUK];
    __shared__ int bb[NBUK];
    int tid = threadIdx.x;
    for (int i = tid; i < NBUK; i += 1024) { hist[i] = 0; ofs[i] = 0; }
    __syncthreads();
    int base = blockIdx.x * EPB + tid * 8;
    int sv[8], dv[8];
#pragma unroll
    for (int j = 0; j < 8; j += 4) {
        if (base + j + 3 < NE) {
            int4 s4 = *reinterpret_cast<const int4*>(src + base + j);
            int4 d4 = *reinterpret_cast<const int4*>(dst + base + j);
            sv[j] = s4.x; sv[j+1] = s4.y; sv[j+2] = s4.z; sv[j+3] = s4.w;
            dv[j] = d4.x; dv[j+1] = d4.y; dv[j+2] = d4.z; dv[j+3] = d4.w;
        } else {
#pragma unroll
            for (int i = 0; i < 4; ++i) {
                int e = base + j + i;
                sv[j+i] = (e < NE) ? src[e] : -1;
                dv[j+i] = (e < NE) ? dst[e] : 0;
            }
        }
    }
#pragma unroll
    for (int j = 0; j < 8; ++j)
        if (sv[j] >= 0) atomicAdd(&hist[dv[j] >> 8], 1);
    __syncthreads();
    for (int b = tid; b < NBUK; b += 1024) {
        int h = hist[b];
        gb[b] = h ? atomicAdd(&bfill[b], h) : 0;
        int cellHi = (b + 1) << 8; if (cellHi > NN) cellHi = NN;
        bb[b] = rowp[b << 8];
        (void)cellHi;
    }
    __syncthreads();
#pragma unroll
    for (int j = 0; j < 8; ++j) {
        if (sv[j] >= 0) {
            int b = dv[j] >> 8;
            int p = atomicAdd(&ofs[b], 1);
            staged[bb[b] + gb[b] + p] = sv[j] | ((dv[j] & 255) << 17);
        }
    }
}

// Pass B: per-bucket LDS counting sort -> csr (byte offsets src*128),
// sequential writes within the bucket's CSR region.
__global__ __launch_bounds__(256)
void k_bsort(const int* __restrict__ staged, const int* __restrict__ rowp,
             int* __restrict__ csr) {
    __shared__ int cnt[256];
    __shared__ int wsum[4];
    int b = blockIdx.x, tid = threadIdx.x;
    int lo = rowp[b << 8];
    int dHi = (b + 1) << 8; if (dHi > NN) dHi = NN;
    int hi = rowp[dHi];
    cnt[tid] = 0;
    __syncthreads();
    for (int i = lo + tid; i < hi; i += 256)
        atomicAdd(&cnt[(staged[i] >> 17) & 255], 1);
    __syncthreads();
    int c = cnt[tid];
    int lane = tid & 63, w = tid >> 6;
    int inc = c;
    for (int o = 1; o < 64; o <<= 1) {
        int u = __shfl_up(inc, o, 64);
        if (lane >= o) inc += u;
    }
    if (lane == 63) wsum[w] = inc;
    __syncthreads();
    int woff = 0;
#pragma unroll
    for (int i = 0; i < 4; ++i) if (i < w) woff += wsum[i];
    int ex = woff + inc - c;
    __syncthreads();
    cnt[tid] = ex;
    __syncthreads();
    for (int i = lo + tid; i < hi; i += 256) {
        int u = staged[i];
        int p = atomicAdd(&cnt[(u >> 17) & 255], 1);
        csr[lo + p] = (u & 0x1FFFF) * ROWB;
    }
}

// ---------- error build + sigma (two-stage, no global atomics) ----------
__global__ void k_error(const float* __restrict__ y_soft, const int* __restrict__ y_true,
                        const int* __restrict__ train, const float* __restrict__ norm,
                        __half* __restrict__ A, __half* __restrict__ last,
                        float* __restrict__ partial) {
    int t = blockIdx.x * blockDim.x + threadIdx.x;
    float a = 0.f;
    if (t < NTR * 12) {
        int j = t / 12, ch = (t % 12) * 4;
        int yt = y_true[j];
        float4 ys = *reinterpret_cast<const float4*>(y_soft + (size_t)j * NC + ch);
        float e0 = ((ch + 0 == yt) ? 1.f : 0.f) - ys.x;
        float e1 = ((ch + 1 == yt) ? 1.f : 0.f) - ys.y;
        float e2 = ((ch + 2 == yt) ? 1.f : 0.f) - ys.z;
        float e3 = ((ch + 3 == yt) ? 1.f : 0.f) - ys.w;
        int r = train[j];
        float w = norm[r];
        *reinterpret_cast<uint2*>(A + (size_t)r * ROWH + ch) =
            f4h(make_float4(w * e0, w * e1, w * e2, w * e3));
        float la = 1.0f - ALPHA1;
        *reinterpret_cast<uint2*>(last + (size_t)r * ROWH + ch) =
            f4h(make_float4(la * e0, la * e1, la * e2, la * e3));
        a = fabsf(e0) + fabsf(e1) + fabsf(e2) + fabsf(e3);
    }
    for (int o = 32; o > 0; o >>= 1) a += __shfl_down(a, o, 64);
    __shared__ float sh[4];
    if ((threadIdx.x & 63) == 0) sh[threadIdx.x >> 6] = a;
    __syncthreads();
    if (threadIdx.x == 0) partial[blockIdx.x] = sh[0] + sh[1] + sh[2] + sh[3];
}

__global__ void k_sigsum(const float* __restrict__ partial, float* __restrict__ sig) {
    float a = 0.f;
    for (int i = threadIdx.x; i < NEB; i += 512) a += partial[i];
    for (int o = 32; o > 0; o >>= 1) a += __shfl_down(a, o, 64);
    __shared__ float sh[8];
    if ((threadIdx.x & 63) == 0) sh[threadIdx.x >> 6] = a;
    __syncthreads();
    if (threadIdx.x == 0) {
        float s = 0.f;
#pragma unroll
        for (int i = 0; i < 8; ++i) s += sh[i];
        sig[0] = s;
    }
}

// ---------- propagation layer (R6 form: flat loop, unroll-8) ----------
template <bool PRE>
__global__ __launch_bounds__(256)
void k_gather(const __half* __restrict__ yin, __half* __restrict__ yout,
              const __half* __restrict__ last, const float* __restrict__ norm,
              const int* __restrict__ rowp, const int* __restrict__ csrB,
              float alpha, float lo, float hi) {
    int t = blockIdx.x * blockDim.x + threadIdx.x;
    if (t >= NN * 6) return;
    int node = t / 6, chb = (t % 6) * 16;
    const char* yb = reinterpret_cast<const char*>(yin) + chb;
    int beg = rowp[node], end = rowp[node + 1];
    float4 A0 = make_float4(0, 0, 0, 0), B0 = make_float4(0, 0, 0, 0);
    float4 A1 = make_float4(0, 0, 0, 0), B1 = make_float4(0, 0, 0, 0);
    int k = beg;
    for (; k + 8 <= end; k += 8) {
        int o0 = csrB[k],     o1 = csrB[k + 1], o2 = csrB[k + 2], o3 = csrB[k + 3];
        int o4 = csrB[k + 4], o5 = csrB[k + 5], o6 = csrB[k + 6], o7 = csrB[k + 7];
        uint4 q0 = *reinterpret_cast<const uint4*>(yb + o0);
        uint4 q1 = *reinterpret_cast<const uint4*>(yb + o1);
        uint4 q2 = *reinterpret_cast<const uint4*>(yb + o2);
        uint4 q3 = *reinterpret_cast<const uint4*>(yb + o3);
        uint4 q4 = *reinterpret_cast<const uint4*>(yb + o4);
        uint4 q5 = *reinterpret_cast<const uint4*>(yb + o5);
        uint4 q6 = *reinterpret_cast<const uint4*>(yb + o6);
        uint4 q7 = *reinterpret_cast<const uint4*>(yb + o7);
        h8acc(q0, A0, B0); h8acc(q1, A1, B1);
        h8acc(q2, A0, B0); h8acc(q3, A1, B1);
        h8acc(q4, A0, B0); h8acc(q5, A1, B1);
        h8acc(q6, A0, B0); h8acc(q7, A1, B1);
    }
    for (; k < end; ++k) {
        uint4 q = *reinterpret_cast<const uint4*>(yb + csrB[k]);
        h8acc(q, A0, B0);
    }
    A0.x += A1.x; A0.y += A1.y; A0.z += A1.z; A0.w += A1.w;
    B0.x += B1.x; B0.y += B1.y; B0.z += B1.z; B0.w += B1.w;

    float nd = alpha * norm[node];
    const char* lb = reinterpret_cast<const char*>(last) + (size_t)node * ROWB + chb;
    H8 lt; lt.u = *reinterpret_cast<const uint4*>(lb);
    float2 l0 = __half22float2(lt.h[0]), l1 = __half22float2(lt.h[1]);
    float2 l2 = __half22float2(lt.h[2]), l3 = __half22float2(lt.h[3]);
    float o0 = fminf(fmaxf(fmaf(nd, A0.x, l0.x), lo), hi);
    float o1 = fminf(fmaxf(fmaf(nd, A0.y, l0.y), lo), hi);
    float o2 = fminf(fmaxf(fmaf(nd, A0.z, l1.x), lo), hi);
    float o3 = fminf(fmaxf(fmaf(nd, A0.w, l1.y), lo), hi);
    float o4 = fminf(fmaxf(fmaf(nd, B0.x, l2.x), lo), hi);
    float o5 = fminf(fmaxf(fmaf(nd, B0.y, l2.y), lo), hi);
    float o6 = fminf(fmaxf(fmaf(nd, B0.z, l3.x), lo), hi);
    float o7 = fminf(fmaxf(fmaf(nd, B0.w, l3.y), lo), hi);
    if (PRE) {
        float w = norm[node];
        o0 *= w; o1 *= w; o2 *= w; o3 *= w; o4 *= w; o5 *= w; o6 *= w; o7 *= w;
    }
    H8 ot;
    ot.h[0] = __float22half2_rn(make_float2(o0, o1));
    ot.h[1] = __float22half2_rn(make_float2(o2, o3));
    ot.h[2] = __float22half2_rn(make_float2(o4, o5));
    ot.h[3] = __float22half2_rn(make_float2(o6, o7));
    char* ob = reinterpret_cast<char*>(yout) + (size_t)node * ROWB + chb;
    *reinterpret_cast<uint4*>(ob) = ot.u;
}

// ---------- scale prep ----------
__global__ void k_rowabs(const __half* __restrict__ se, float* __restrict__ rowabs) {
    int v = blockIdx.x * blockDim.x + threadIdx.x;
    if (v >= NN) return;
    const uint4* p = reinterpret_cast<const uint4*>(se + (size_t)v * ROWH);
    float s = 0.f;
#pragma unroll
    for (int k = 0; k < 6; ++k) {
        H8 t; t.u = p[k];
        float2 f0 = __half22float2(t.h[0]), f1 = __half22float2(t.h[1]);
        float2 f2 = __half22float2(t.h[2]), f3 = __half22float2(t.h[3]);
        s += fabsf(f0.x) + fabsf(f0.y) + fabsf(f1.x) + fabsf(f1.y)
           + fabsf(f2.x) + fabsf(f2.y) + fabsf(f3.x) + fabsf(f3.y);
    }
    rowabs[v] = s;
}

__device__ __forceinline__ int cat_at(int i, const int* __restrict__ tr,
                                      const int* __restrict__ va, const int* __restrict__ te) {
    if (i < NTR)        return tr[i];
    if (i < NTR + NVA)  return va[i - NTR];
    return te[i - NTR - NVA];
}

// In-place on A (unscaled smoothed_error in, pre-scaled y_all out).
__global__ void k_phaseD(__half* __restrict__ se_yall, const float* __restrict__ y_soft,
                         const float* __restrict__ rowabs, const float* __restrict__ sig,
                         const int* __restrict__ y_true,
                         const int* __restrict__ tr, const int* __restrict__ va,
                         const int* __restrict__ te, const float* __restrict__ norm,
                         __half* __restrict__ last) {
    int t = blockIdx.x * blockDim.x + threadIdx.x;
    if (t >= NN * 12) return;
    int i = t / 12, ch = (t % 12) * 4;
    int cid = cat_at(i, tr, va, te);
    float4 o;
    if (i < NTR) {
        int yt = y_true[i];
        o.x = (ch + 0 == yt) ? 1.f : 0.f;
        o.y = (ch + 1 == yt) ? 1.f : 0.f;
        o.z = (ch + 2 == yt) ? 1.f : 0.f;
        o.w = (ch + 3 == yt) ? 1.f : 0.f;
    } else {
        float s = (sig[0] * (1.0f / NTR)) / rowabs[i];
        if (s > 1000.0f) s = 1.0f;
        float4 e  = h4f(*reinterpret_cast<const uint2*>(se_yall + (size_t)cid * ROWH + ch));
        float4 ys = *reinterpret_cast<const float4*>(y_soft + (size_t)i * NC + ch);
        o.x = ys.x + s * e.x; if (o.x != o.x) o.x = ys.x;
        o.y = ys.y + s * e.y; if (o.y != o.y) o.y = ys.y;
        o.z = ys.z + s * e.z; if (o.z != o.z) o.z = ys.z;
        o.w = ys.w + s * e.w; if (o.w != o.w) o.w = ys.w;
    }
    float w = norm[cid];
    *reinterpret_cast<uint2*>(se_yall + (size_t)cid * ROWH + ch) =
        f4h(make_float4(o.x * w, o.y * w, o.z * w, o.w * w));
    float la = 1.0f - ALPHA2;
    *reinterpret_cast<uint2*>(last + (size_t)cid * ROWH + ch) =
        f4h(make_float4(la * o.x, la * o.y, la * o.z, la * o.w));
}

// out[i] = yin[cat[i]]  (fp16 padded -> f32 dense)
__global__ void k_outgather(const __half* __restrict__ yin, float* __restrict__ out,
                            const int* __restrict__ tr, const int* __restrict__ va,
                            const int* __restrict__ te) {
    int t = blockIdx.x * blockDim.x + threadIdx.x;
    if (t >= NN * 12) return;
    int i = t / 12, ch = (t % 12) * 4;
    int cid = cat_at(i, tr, va, te);
    float4 v = h4f(*reinterpret_cast<const uint2*>(yin + (size_t)cid * ROWH + ch));
    *reinterpret_cast<float4*>(out + (size_t)i * NC + ch) = v;
}

extern "C" void kernel_launch(void* const* d_in, const int* in_sizes, int n_in,
                              void* d_out, int out_size, void* d_ws, size_t ws_size,
                              hipStream_t stream) {
    const float* y_soft = (const float*)d_in[0];
    const int*   y_true = (const int*)d_in[1];
    const int*   src    = (const int*)d_in[2];
    const int*   dst    = (const int*)d_in[3];
    const int*   tr     = (const int*)d_in[4];
    const int*   va     = (const int*)d_in[5];
    const int*   te     = (const int*)d_in[6];
    float* out = (float*)d_out;

    char* ws = (char*)d_ws;
    size_t off = 0;
    auto alloc = [&](size_t bytes) -> void* {
        void* p = ws + off;
        off += (bytes + 255) & ~(size_t)255;
        return p;
    };
    __half* A      = (__half*)alloc((size_t)NN * ROWH * 2);   // 12.8 MB
    __half* B      = (__half*)alloc((size_t)NN * ROWH * 2);   // 12.8 MB
    __half* last   = (__half*)alloc((size_t)NN * ROWH * 2);   // 12.8 MB
    int*    csr    = (int*)   alloc((size_t)NE * 4);          // 6.4 MB
    int*    staged = (int*)   alloc((size_t)NE * 4);          // 6.4 MB
    int*    deg    = (int*)   alloc((size_t)NN * 4);
    int*    rowp   = (int*)   alloc((size_t)(NN + 1) * 4);
    int*    bfill  = (int*)   alloc((size_t)NBUK * 4);
    float*  norm   = (float*) alloc((size_t)NN * 4);
    float*  rowabs = (float*) alloc((size_t)NN * 4);
    int*    bsum   = (int*)   alloc((size_t)NB * 4);
    float*  partial= (float*) alloc((size_t)NEB * 4);
    float*  sig    = (float*) alloc(256);

    (void)hipMemsetAsync(deg,   0, (size_t)NN * 4, stream);
    (void)hipMemsetAsync(bfill, 0, (size_t)NBUK * 4, stream);
    (void)hipMemsetAsync(A,     0, (size_t)NN * ROWH * 2, stream);
    (void)hipMemsetAsync(last,  0, (size_t)NN * ROWH * 2, stream);

    k_count  <<<NE / 256, 256, 0, stream>>>(dst, deg);
    k_bsum   <<<NB, 256, 0, stream>>>(deg, bsum);
    k_bscan  <<<1, 128, 0, stream>>>(bsum);
    k_scatter<<<NB, 256, 0, stream>>>(deg, bsum, rowp);
    k_norm   <<<(NN + 255) / 256, 256, 0, stream>>>(rowp, norm);
    k_stage2 <<<NSB, 1024, 0, stream>>>(src, dst, rowp, bfill, staged);
    k_bsort  <<<NBUK, 256, 0, stream>>>(staged, rowp, csr);
    k_error  <<<NEB, 256, 0, stream>>>(y_soft, y_true, tr, norm, A, last, partial);
    k_sigsum <<<1, 512, 0, stream>>>(partial, sig);

    const int G6  = (NN * 6 + 255) / 256;
    const int G12 = (NN * 12 + 255) / 256;

    // propagation 1: A -> ... -> A (10 layers); last layer unscaled
    __half* cur = A; __half* oth = B;
    for (int l = 0; l < 10; ++l) {
        if (l < 9)
            k_gather<true><<<G6, 256, 0, stream>>>(cur, oth, last, norm, rowp, csr,
                                                   ALPHA1, -1.f, 1.f);
        else
            k_gather<false><<<G6, 256, 0, stream>>>(cur, oth, last, norm, rowp, csr,
                                                    ALPHA1, -1.f, 1.f);
        __half* t2 = cur; cur = oth; oth = t2;
    }

    k_rowabs<<<(NN + 255) / 256, 256, 0, stream>>>(A, rowabs);
    // in-place: A := norm .* y_all; last := (1-ALPHA2)*y_all
    k_phaseD<<<G12, 256, 0, stream>>>(A, y_soft, rowabs, sig, y_true,
                                      tr, va, te, norm, last);

    // propagation 2: A -> ... -> A (10 layers); last layer unscaled
    cur = A; oth = B;
    for (int l = 0; l < 10; ++l) {
        if (l < 9)
            k_gather<true><<<G6, 256, 0, stream>>>(cur, oth, last, norm, rowp, csr,
                                                   ALPHA2, 0.f, 1.f);
        else
            k_gather<false><<<G6, 256, 0, stream>>>(cur, oth, last, norm, rowp, csr,
                                                    ALPHA2, 0.f, 1.f);
        __half* t2 = cur; cur = oth; oth = t2;
    }

    // d_out[i] = A[cat[i]]
    k_outgather<<<G12, 256, 0, stream>>>(A, out, tr, va, te);
}

// Round 12
// 747.355 us; speedup vs baseline: 1.7917x; 1.0823x over previous
//
#include <hip/hip_runtime.h>
#include <hip/hip_fp16.h>

// CorrectAndSmooth on MI355X.
// N=100000 nodes, C=48 classes, E=1.6M edges, 10+10 propagation layers.
// R11: eliminate per-node count+scan (k_count was 66us of atomic write-amp).
//      Bucket-granular count (LDS, 391 counters) -> bucket scan -> stage ->
//      per-bucket sort which also emits rowp (per-node prefix for free).

constexpr int NN  = 100000;
constexpr int NC  = 48;
constexpr int NE  = 1600000;
constexpr int NTR = 10000;
constexpr int NVA = 10000;
constexpr float ALPHA1 = 0.979f;
constexpr float ALPHA2 = 0.756f;
constexpr int ROWH = 64;           // halfs per padded row (128B)
constexpr int ROWB = 128;          // bytes per padded row

constexpr int NBUK = (NN + 255) / 256;            // 391 dst buckets
constexpr int EPB  = 8192;                        // edges per block (count/stage)
constexpr int NSB  = (NE + EPB - 1) / EPB;        // 196 blocks
constexpr int NEB  = (NTR * 12 + 255) / 256;      // k_error blocks

union H4 { uint2 u; __half2 h[2]; };

__device__ __forceinline__ float4 h4f(uint2 q) {
    H4 t; t.u = q;
    float2 a = __half22float2(t.h[0]), b = __half22float2(t.h[1]);
    return make_float4(a.x, a.y, b.x, b.y);
}
__device__ __forceinline__ uint2 f4h(float4 v) {
    H4 t;
    t.h[0] = __float22half2_rn(make_float2(v.x, v.y));
    t.h[1] = __float22half2_rn(make_float2(v.z, v.w));
    return t.u;
}

union H8 { uint4 u; __half2 h[4]; };

__device__ __forceinline__ void h8acc(uint4 q, float4& A, float4& B) {
    H8 t; t.u = q;
    float2 f0 = __half22float2(t.h[0]), f1 = __half22float2(t.h[1]);
    float2 f2 = __half22float2(t.h[2]), f3 = __half22float2(t.h[3]);
    A.x += f0.x; A.y += f0.y; A.z += f1.x; A.w += f1.y;
    B.x += f2.x; B.y += f2.y; B.z += f3.x; B.w += f3.y;
}

// ---------- CSR build ----------

// per-bucket histogram with LDS aggregation (391 counters)
__global__ __launch_bounds__(1024)
void k_countb(const int* __restrict__ dst, int* __restrict__ bukcnt) {
    __shared__ int hist[NBUK];
    int tid = threadIdx.x;
    for (int i = tid; i < NBUK; i += 1024) hist[i] = 0;
    __syncthreads();
    int base = blockIdx.x * EPB + tid * 8;
#pragma unroll
    for (int j = 0; j < 8; j += 4) {
        if (base + j + 3 < NE) {
            int4 d4 = *reinterpret_cast<const int4*>(dst + base + j);
            atomicAdd(&hist[d4.x >> 8], 1);
            atomicAdd(&hist[d4.y >> 8], 1);
            atomicAdd(&hist[d4.z >> 8], 1);
            atomicAdd(&hist[d4.w >> 8], 1);
        } else {
#pragma unroll
            for (int i = 0; i < 4; ++i) {
                int e = base + j + i;
                if (e < NE) atomicAdd(&hist[dst[e] >> 8], 1);
            }
        }
    }
    __syncthreads();
    for (int i = tid; i < NBUK; i += 1024) {
        int h = hist[i];
        if (h) atomicAdd(&bukcnt[i], h);
    }
}

// exclusive scan of 391 bucket counts -> bukp[0..NBUK], bukp[NBUK]=NE
__global__ void k_bukscan(const int* __restrict__ bukcnt, int* __restrict__ bukp) {
    __shared__ int sh[512];
    int t = threadIdx.x;
    int v = (t < NBUK) ? bukcnt[t] : 0;
    sh[t] = v;
    __syncthreads();
    for (int o = 1; o < 512; o <<= 1) {
        int u = (t >= o) ? sh[t - o] : 0;
        __syncthreads();
        sh[t] += u;
        __syncthreads();
    }
    if (t < NBUK) bukp[t] = sh[t] - v;
    if (t == 0) bukp[NBUK] = NE;
}

// stage edges into per-bucket regions: LDS histogram -> one global atomic
// per bucket to reserve a range -> contiguous-run writes.
// word = src | (dst&255)<<17
__global__ __launch_bounds__(1024)
void k_stage2(const int* __restrict__ src, const int* __restrict__ dst,
              const int* __restrict__ bukp, int* __restrict__ bfill,
              int* __restrict__ staged) {
    __shared__ int hist[NBUK];
    __shared__ int gb[NBUK];
    __shared__ int ofs[NBUK];
    __shared__ int bb[NBUK];
    int tid = threadIdx.x;
    for (int i = tid; i < NBUK; i += 1024) { hist[i] = 0; ofs[i] = 0; }
    __syncthreads();
    int base = blockIdx.x * EPB + tid * 8;
    int sv[8], dv[8];
#pragma unroll
    for (int j = 0; j < 8; j += 4) {
        if (base + j + 3 < NE) {
            int4 s4 = *reinterpret_cast<const int4*>(src + base + j);
            int4 d4 = *reinterpret_cast<const int4*>(dst + base + j);
            sv[j] = s4.x; sv[j+1] = s4.y; sv[j+2] = s4.z; sv[j+3] = s4.w;
            dv[j] = d4.x; dv[j+1] = d4.y; dv[j+2] = d4.z; dv[j+3] = d4.w;
        } else {
#pragma unroll
            for (int i = 0; i < 4; ++i) {
                int e = base + j + i;
                sv[j+i] = (e < NE) ? src[e] : -1;
                dv[j+i] = (e < NE) ? dst[e] : 0;
            }
        }
    }
#pragma unroll
    for (int j = 0; j < 8; ++j)
        if (sv[j] >= 0) atomicAdd(&hist[dv[j] >> 8], 1);
    __syncthreads();
    for (int b = tid; b < NBUK; b += 1024) {
        int h = hist[b];
        gb[b] = h ? atomicAdd(&bfill[b], h) : 0;
        bb[b] = bukp[b];
    }
    __syncthreads();
#pragma unroll
    for (int j = 0; j < 8; ++j) {
        if (sv[j] >= 0) {
            int b = dv[j] >> 8;
            int p = atomicAdd(&ofs[b], 1);
            staged[bb[b] + gb[b] + p] = sv[j] | ((dv[j] & 255) << 17);
        }
    }
}

// per-bucket LDS counting sort -> csr (byte offsets src*128); also emits
// rowp[d] = bucket base + exclusive prefix of local counts.
__global__ __launch_bounds__(256)
void k_bsort(const int* __restrict__ staged, const int* __restrict__ bukp,
             int* __restrict__ csr, int* __restrict__ rowp) {
    __shared__ int cnt[256];
    __shared__ int wsum[4];
    int b = blockIdx.x, tid = threadIdx.x;
    int lo = bukp[b], hi = bukp[b + 1];
    cnt[tid] = 0;
    __syncthreads();
    for (int i = lo + tid; i < hi; i += 256)
        atomicAdd(&cnt[(staged[i] >> 17) & 255], 1);
    __syncthreads();
    int c = cnt[tid];
    int lane = tid & 63, w = tid >> 6;
    int inc = c;
    for (int o = 1; o < 64; o <<= 1) {
        int u = __shfl_up(inc, o, 64);
        if (lane >= o) inc += u;
    }
    if (lane == 63) wsum[w] = inc;
    __syncthreads();
    int woff = 0;
#pragma unroll
    for (int i = 0; i < 4; ++i) if (i < w) woff += wsum[i];
    int ex = woff + inc - c;
    int node = (b << 8) + tid;
    if (node < NN) rowp[node] = lo + ex;
    if (b == 0 && tid == 0) rowp[NN] = NE;
    __syncthreads();
    cnt[tid] = ex;
    __syncthreads();
    for (int i = lo + tid; i < hi; i += 256) {
        int u = staged[i];
        int p = atomicAdd(&cnt[(u >> 17) & 255], 1);
        csr[lo + p] = (u & 0x1FFFF) * ROWB;
    }
}

__global__ void k_norm(const int* __restrict__ rowp, float* __restrict__ norm) {
    int v = blockIdx.x * blockDim.x + threadIdx.x;
    if (v < NN) {
        int d = rowp[v + 1] - rowp[v];
        if (d < 1) d = 1;
        norm[v] = rsqrtf((float)d);
    }
}

// ---------- error build + sigma (two-stage, no global atomics) ----------
__global__ void k_error(const float* __restrict__ y_soft, const int* __restrict__ y_true,
                        const int* __restrict__ train, const float* __restrict__ norm,
                        __half* __restrict__ A, __half* __restrict__ last,
                        float* __restrict__ partial) {
    int t = blockIdx.x * blockDim.x + threadIdx.x;
    float a = 0.f;
    if (t < NTR * 12) {
        int j = t / 12, ch = (t % 12) * 4;
        int yt = y_true[j];
        float4 ys = *reinterpret_cast<const float4*>(y_soft + (size_t)j * NC + ch);
        float e0 = ((ch + 0 == yt) ? 1.f : 0.f) - ys.x;
        float e1 = ((ch + 1 == yt) ? 1.f : 0.f) - ys.y;
        float e2 = ((ch + 2 == yt) ? 1.f : 0.f) - ys.z;
        float e3 = ((ch + 3 == yt) ? 1.f : 0.f) - ys.w;
        int r = train[j];
        float w = norm[r];
        *reinterpret_cast<uint2*>(A + (size_t)r * ROWH + ch) =
            f4h(make_float4(w * e0, w * e1, w * e2, w * e3));
        float la = 1.0f - ALPHA1;
        *reinterpret_cast<uint2*>(last + (size_t)r * ROWH + ch) =
            f4h(make_float4(la * e0, la * e1, la * e2, la * e3));
        a = fabsf(e0) + fabsf(e1) + fabsf(e2) + fabsf(e3);
    }
    for (int o = 32; o > 0; o >>= 1) a += __shfl_down(a, o, 64);
    __shared__ float sh[4];
    if ((threadIdx.x & 63) == 0) sh[threadIdx.x >> 6] = a;
    __syncthreads();
    if (threadIdx.x == 0) partial[blockIdx.x] = sh[0] + sh[1] + sh[2] + sh[3];
}

__global__ void k_sigsum(const float* __restrict__ partial, float* __restrict__ sig) {
    float a = 0.f;
    for (int i = threadIdx.x; i < NEB; i += 512) a += partial[i];
    for (int o = 32; o > 0; o >>= 1) a += __shfl_down(a, o, 64);
    __shared__ float sh[8];
    if ((threadIdx.x & 63) == 0) sh[threadIdx.x >> 6] = a;
    __syncthreads();
    if (threadIdx.x == 0) {
        float s = 0.f;
#pragma unroll
        for (int i = 0; i < 8; ++i) s += sh[i];
        sig[0] = s;
    }
}

// ---------- propagation layer (flat loop, unroll-8) ----------
template <bool PRE>
__global__ __launch_bounds__(256)
void k_gather(const __half* __restrict__ yin, __half* __restrict__ yout,
              const __half* __restrict__ last, const float* __restrict__ norm,
              const int* __restrict__ rowp, const int* __restrict__ csrB,
              float alpha, float lo, float hi) {
    int t = blockIdx.x * blockDim.x + threadIdx.x;
    if (t >= NN * 6) return;
    int node = t / 6, chb = (t % 6) * 16;
    const char* yb = reinterpret_cast<const char*>(yin) + chb;
    int beg = rowp[node], end = rowp[node + 1];
    float4 A0 = make_float4(0, 0, 0, 0), B0 = make_float4(0, 0, 0, 0);
    float4 A1 = make_float4(0, 0, 0, 0), B1 = make_float4(0, 0, 0, 0);
    int k = beg;
    for (; k + 8 <= end; k += 8) {
        int o0 = csrB[k],     o1 = csrB[k + 1], o2 = csrB[k + 2], o3 = csrB[k + 3];
        int o4 = csrB[k + 4], o5 = csrB[k + 5], o6 = csrB[k + 6], o7 = csrB[k + 7];
        uint4 q0 = *reinterpret_cast<const uint4*>(yb + o0);
        uint4 q1 = *reinterpret_cast<const uint4*>(yb + o1);
        uint4 q2 = *reinterpret_cast<const uint4*>(yb + o2);
        uint4 q3 = *reinterpret_cast<const uint4*>(yb + o3);
        uint4 q4 = *reinterpret_cast<const uint4*>(yb + o4);
        uint4 q5 = *reinterpret_cast<const uint4*>(yb + o5);
        uint4 q6 = *reinterpret_cast<const uint4*>(yb + o6);
        uint4 q7 = *reinterpret_cast<const uint4*>(yb + o7);
        h8acc(q0, A0, B0); h8acc(q1, A1, B1);
        h8acc(q2, A0, B0); h8acc(q3, A1, B1);
        h8acc(q4, A0, B0); h8acc(q5, A1, B1);
        h8acc(q6, A0, B0); h8acc(q7, A1, B1);
    }
    for (; k < end; ++k) {
        uint4 q = *reinterpret_cast<const uint4*>(yb + csrB[k]);
        h8acc(q, A0, B0);
    }
    A0.x += A1.x; A0.y += A1.y; A0.z += A1.z; A0.w += A1.w;
    B0.x += B1.x; B0.y += B1.y; B0.z += B1.z; B0.w += B1.w;

    float nd = alpha * norm[node];
    const char* lb = reinterpret_cast<const char*>(last) + (size_t)node * ROWB + chb;
    H8 lt; lt.u = *reinterpret_cast<const uint4*>(lb);
    float2 l0 = __half22float2(lt.h[0]), l1 = __half22float2(lt.h[1]);
    float2 l2 = __half22float2(lt.h[2]), l3 = __half22float2(lt.h[3]);
    float o0 = fminf(fmaxf(fmaf(nd, A0.x, l0.x), lo), hi);
    float o1 = fminf(fmaxf(fmaf(nd, A0.y, l0.y), lo), hi);
    float o2 = fminf(fmaxf(fmaf(nd, A0.z, l1.x), lo), hi);
    float o3 = fminf(fmaxf(fmaf(nd, A0.w, l1.y), lo), hi);
    float o4 = fminf(fmaxf(fmaf(nd, B0.x, l2.x), lo), hi);
    float o5 = fminf(fmaxf(fmaf(nd, B0.y, l2.y), lo), hi);
    float o6 = fminf(fmaxf(fmaf(nd, B0.z, l3.x), lo), hi);
    float o7 = fminf(fmaxf(fmaf(nd, B0.w, l3.y), lo), hi);
    if (PRE) {
        float w = norm[node];
        o0 *= w; o1 *= w; o2 *= w; o3 *= w; o4 *= w; o5 *= w; o6 *= w; o7 *= w;
    }
    H8 ot;
    ot.h[0] = __float22half2_rn(make_float2(o0, o1));
    ot.h[1] = __float22half2_rn(make_float2(o2, o3));
    ot.h[2] = __float22half2_rn(make_float2(o4, o5));
    ot.h[3] = __float22half2_rn(make_float2(o6, o7));
    char* ob = reinterpret_cast<char*>(yout) + (size_t)node * ROWB + chb;
    *reinterpret_cast<uint4*>(ob) = ot.u;
}

// ---------- scale prep ----------
__global__ void k_rowabs(const __half* __restrict__ se, float* __restrict__ rowabs) {
    int v = blockIdx.x * blockDim.x + threadIdx.x;
    if (v >= NN) return;
    const uint4* p = reinterpret_cast<const uint4*>(se + (size_t)v * ROWH);
    float s = 0.f;
#pragma unroll
    for (int k = 0; k < 6; ++k) {
        H8 t; t.u = p[k];
        float2 f0 = __half22float2(t.h[0]), f1 = __half22float2(t.h[1]);
        float2 f2 = __half22float2(t.h[2]), f3 = __half22float2(t.h[3]);
        s += fabsf(f0.x) + fabsf(f0.y) + fabsf(f1.x) + fabsf(f1.y)
           + fabsf(f2.x) + fabsf(f2.y) + fabsf(f3.x) + fabsf(f3.y);
    }
    rowabs[v] = s;
}

__device__ __forceinline__ int cat_at(int i, const int* __restrict__ tr,
                                      const int* __restrict__ va, const int* __restrict__ te) {
    if (i < NTR)        return tr[i];
    if (i < NTR + NVA)  return va[i - NTR];
    return te[i - NTR - NVA];
}

// In-place on A (unscaled smoothed_error in, pre-scaled y_all out).
__global__ void k_phaseD(__half* __restrict__ se_yall, const float* __restrict__ y_soft,
                         const float* __restrict__ rowabs, const float* __restrict__ sig,
                         const int* __restrict__ y_true,
                         const int* __restrict__ tr, const int* __restrict__ va,
                         const int* __restrict__ te, const float* __restrict__ norm,
                         __half* __restrict__ last) {
    int t = blockIdx.x * blockDim.x + threadIdx.x;
    if (t >= NN * 12) return;
    int i = t / 12, ch = (t % 12) * 4;
    int cid = cat_at(i, tr, va, te);
    float4 o;
    if (i < NTR) {
        int yt = y_true[i];
        o.x = (ch + 0 == yt) ? 1.f : 0.f;
        o.y = (ch + 1 == yt) ? 1.f : 0.f;
        o.z = (ch + 2 == yt) ? 1.f : 0.f;
        o.w = (ch + 3 == yt) ? 1.f : 0.f;
    } else {
        float s = (sig[0] * (1.0f / NTR)) / rowabs[i];
        if (s > 1000.0f) s = 1.0f;
        float4 e  = h4f(*reinterpret_cast<const uint2*>(se_yall + (size_t)cid * ROWH + ch));
        float4 ys = *reinterpret_cast<const float4*>(y_soft + (size_t)i * NC + ch);
        o.x = ys.x + s * e.x; if (o.x != o.x) o.x = ys.x;
        o.y = ys.y + s * e.y; if (o.y != o.y) o.y = ys.y;
        o.z = ys.z + s * e.z; if (o.z != o.z) o.z = ys.z;
        o.w = ys.w + s * e.w; if (o.w != o.w) o.w = ys.w;
    }
    float w = norm[cid];
    *reinterpret_cast<uint2*>(se_yall + (size_t)cid * ROWH + ch) =
        f4h(make_float4(o.x * w, o.y * w, o.z * w, o.w * w));
    float la = 1.0f - ALPHA2;
    *reinterpret_cast<uint2*>(last + (size_t)cid * ROWH + ch) =
        f4h(make_float4(la * o.x, la * o.y, la * o.z, la * o.w));
}

// out[i] = yin[cat[i]]  (fp16 padded -> f32 dense)
__global__ void k_outgather(const __half* __restrict__ yin, float* __restrict__ out,
                            const int* __restrict__ tr, const int* __restrict__ va,
                            const int* __restrict__ te) {
    int t = blockIdx.x * blockDim.x + threadIdx.x;
    if (t >= NN * 12) return;
    int i = t / 12, ch = (t % 12) * 4;
    int cid = cat_at(i, tr, va, te);
    float4 v = h4f(*reinterpret_cast<const uint2*>(yin + (size_t)cid * ROWH + ch));
    *reinterpret_cast<float4*>(out + (size_t)i * NC + ch) = v;
}

extern "C" void kernel_launch(void* const* d_in, const int* in_sizes, int n_in,
                              void* d_out, int out_size, void* d_ws, size_t ws_size,
                              hipStream_t stream) {
    const float* y_soft = (const float*)d_in[0];
    const int*   y_true = (const int*)d_in[1];
    const int*   src    = (const int*)d_in[2];
    const int*   dst    = (const int*)d_in[3];
    const int*   tr     = (const int*)d_in[4];
    const int*   va     = (const int*)d_in[5];
    const int*   te     = (const int*)d_in[6];
    float* out = (float*)d_out;

    char* ws = (char*)d_ws;
    size_t off = 0;
    auto alloc = [&](size_t bytes) -> void* {
        void* p = ws + off;
        off += (bytes + 255) & ~(size_t)255;
        return p;
    };
    __half* A      = (__half*)alloc((size_t)NN * ROWH * 2);   // 12.8 MB
    __half* B      = (__half*)alloc((size_t)NN * ROWH * 2);   // 12.8 MB
    __half* last   = (__half*)alloc((size_t)NN * ROWH * 2);   // 12.8 MB
    int*    csr    = (int*)   alloc((size_t)NE * 4);          // 6.4 MB
    int*    staged = (int*)   alloc((size_t)NE * 4);          // 6.4 MB
    int*    rowp   = (int*)   alloc((size_t)(NN + 1) * 4);
    int*    bukcnt = (int*)   alloc((size_t)NBUK * 4);
    int*    bukp   = (int*)   alloc((size_t)(NBUK + 1) * 4);
    int*    bfill  = (int*)   alloc((size_t)NBUK * 4);
    float*  norm   = (float*) alloc((size_t)NN * 4);
    float*  rowabs = (float*) alloc((size_t)NN * 4);
    float*  partial= (float*) alloc((size_t)NEB * 4);
    float*  sig    = (float*) alloc(256);

    (void)hipMemsetAsync(bukcnt, 0, (size_t)NBUK * 4, stream);
    (void)hipMemsetAsync(bfill,  0, (size_t)NBUK * 4, stream);
    (void)hipMemsetAsync(A,      0, (size_t)NN * ROWH * 2, stream);
    (void)hipMemsetAsync(last,   0, (size_t)NN * ROWH * 2, stream);

    k_countb <<<NSB, 1024, 0, stream>>>(dst, bukcnt);
    k_bukscan<<<1, 512, 0, stream>>>(bukcnt, bukp);
    k_stage2 <<<NSB, 1024, 0, stream>>>(src, dst, bukp, bfill, staged);
    k_bsort  <<<NBUK, 256, 0, stream>>>(staged, bukp, csr, rowp);
    k_norm   <<<(NN + 255) / 256, 256, 0, stream>>>(rowp, norm);
    k_error  <<<NEB, 256, 0, stream>>>(y_soft, y_true, tr, norm, A, last, partial);
    k_sigsum <<<1, 512, 0, stream>>>(partial, sig);

    const int G6  = (NN * 6 + 255) / 256;
    const int G12 = (NN * 12 + 255) / 256;

    // propagation 1: A -> ... -> A (10 layers); last layer unscaled
    __half* cur = A; __half* oth = B;
    for (int l = 0; l < 10; ++l) {
        if (l < 9)
            k_gather<true><<<G6, 256, 0, stream>>>(cur, oth, last, norm, rowp, csr,
                                                   ALPHA1, -1.f, 1.f);
        else
            k_gather<false><<<G6, 256, 0, stream>>>(cur, oth, last, norm, rowp, csr,
                                                    ALPHA1, -1.f, 1.f);
        __half* t2 = cur; cur = oth; oth = t2;
    }

    k_rowabs<<<(NN + 255) / 256, 256, 0, stream>>>(A, rowabs);
    // in-place: A := norm .* y_all; last := (1-ALPHA2)*y_all
    k_phaseD<<<G12, 256, 0, stream>>>(A, y_soft, rowabs, sig, y_true,
                                      tr, va, te, norm, last);

    // propagation 2: A -> ... -> A (10 layers); last layer unscaled
    cur = A; oth = B;
    for (int l = 0; l < 10; ++l) {
        if (l < 9)
            k_gather<true><<<G6, 256, 0, stream>>>(cur, oth, last, norm, rowp, csr,
                                                   ALPHA2, 0.f, 1.f);
        else
            k_gather<false><<<G6, 256, 0, stream>>>(cur, oth, last, norm, rowp, csr,
                                                    ALPHA2, 0.f, 1.f);
        __half* t2 = cur; cur = oth; oth = t2;
    }

    // d_out[i] = A[cat[i]]
    k_outgather<<<G12, 256, 0, stream>>>(A, out, tr, va, te);
}

// Round 13
// 739.361 us; speedup vs baseline: 1.8111x; 1.0108x over previous
//
#include <hip/hip_runtime.h>
#include <hip/hip_fp16.h>

// CorrectAndSmooth on MI355X.
// N=100000 nodes, C=48 classes, E=1.6M edges, 10+10 propagation layers.
// R12: fold norm into k_bsort (degree already in LDS there); build inverse
//      permutation inv[] and have the final phase-2 gather write f32 directly
//      to d_out (kills k_outgather pass). Gather core unchanged.

constexpr int NN  = 100000;
constexpr int NC  = 48;
constexpr int NE  = 1600000;
constexpr int NTR = 10000;
constexpr int NVA = 10000;
constexpr float ALPHA1 = 0.979f;
constexpr float ALPHA2 = 0.756f;
constexpr int ROWH = 64;           // halfs per padded row (128B)
constexpr int ROWB = 128;          // bytes per padded row

constexpr int NBUK = (NN + 255) / 256;            // 391 dst buckets
constexpr int EPB  = 8192;                        // edges per block (count/stage)
constexpr int NSB  = (NE + EPB - 1) / EPB;        // 196 blocks
constexpr int NEB  = (NTR * 12 + 255) / 256;      // k_error blocks

union H4 { uint2 u; __half2 h[2]; };

__device__ __forceinline__ float4 h4f(uint2 q) {
    H4 t; t.u = q;
    float2 a = __half22float2(t.h[0]), b = __half22float2(t.h[1]);
    return make_float4(a.x, a.y, b.x, b.y);
}
__device__ __forceinline__ uint2 f4h(float4 v) {
    H4 t;
    t.h[0] = __float22half2_rn(make_float2(v.x, v.y));
    t.h[1] = __float22half2_rn(make_float2(v.z, v.w));
    return t.u;
}

union H8 { uint4 u; __half2 h[4]; };

__device__ __forceinline__ void h8acc(uint4 q, float4& A, float4& B) {
    H8 t; t.u = q;
    float2 f0 = __half22float2(t.h[0]), f1 = __half22float2(t.h[1]);
    float2 f2 = __half22float2(t.h[2]), f3 = __half22float2(t.h[3]);
    A.x += f0.x; A.y += f0.y; A.z += f1.x; A.w += f1.y;
    B.x += f2.x; B.y += f2.y; B.z += f3.x; B.w += f3.y;
}

// ---------- CSR build ----------

// per-bucket histogram with LDS aggregation (391 counters)
__global__ __launch_bounds__(1024)
void k_countb(const int* __restrict__ dst, int* __restrict__ bukcnt) {
    __shared__ int hist[NBUK];
    int tid = threadIdx.x;
    for (int i = tid; i < NBUK; i += 1024) hist[i] = 0;
    __syncthreads();
    int base = blockIdx.x * EPB + tid * 8;
#pragma unroll
    for (int j = 0; j < 8; j += 4) {
        if (base + j + 3 < NE) {
            int4 d4 = *reinterpret_cast<const int4*>(dst + base + j);
            atomicAdd(&hist[d4.x >> 8], 1);
            atomicAdd(&hist[d4.y >> 8], 1);
            atomicAdd(&hist[d4.z >> 8], 1);
            atomicAdd(&hist[d4.w >> 8], 1);
        } else {
#pragma unroll
            for (int i = 0; i < 4; ++i) {
                int e = base + j + i;
                if (e < NE) atomicAdd(&hist[dst[e] >> 8], 1);
            }
        }
    }
    __syncthreads();
    for (int i = tid; i < NBUK; i += 1024) {
        int h = hist[i];
        if (h) atomicAdd(&bukcnt[i], h);
    }
}

// exclusive scan of 391 bucket counts -> bukp[0..NBUK], bukp[NBUK]=NE
__global__ void k_bukscan(const int* __restrict__ bukcnt, int* __restrict__ bukp) {
    __shared__ int sh[512];
    int t = threadIdx.x;
    int v = (t < NBUK) ? bukcnt[t] : 0;
    sh[t] = v;
    __syncthreads();
    for (int o = 1; o < 512; o <<= 1) {
        int u = (t >= o) ? sh[t - o] : 0;
        __syncthreads();
        sh[t] += u;
        __syncthreads();
    }
    if (t < NBUK) bukp[t] = sh[t] - v;
    if (t == 0) bukp[NBUK] = NE;
}

// stage edges into per-bucket regions: LDS histogram -> one global atomic
// per bucket to reserve a range -> contiguous-run writes.
// word = src | (dst&255)<<17
__global__ __launch_bounds__(1024)
void k_stage2(const int* __restrict__ src, const int* __restrict__ dst,
              const int* __restrict__ bukp, int* __restrict__ bfill,
              int* __restrict__ staged) {
    __shared__ int hist[NBUK];
    __shared__ int gb[NBUK];
    __shared__ int ofs[NBUK];
    __shared__ int bb[NBUK];
    int tid = threadIdx.x;
    for (int i = tid; i < NBUK; i += 1024) { hist[i] = 0; ofs[i] = 0; }
    __syncthreads();
    int base = blockIdx.x * EPB + tid * 8;
    int sv[8], dv[8];
#pragma unroll
    for (int j = 0; j < 8; j += 4) {
        if (base + j + 3 < NE) {
            int4 s4 = *reinterpret_cast<const int4*>(src + base + j);
            int4 d4 = *reinterpret_cast<const int4*>(dst + base + j);
            sv[j] = s4.x; sv[j+1] = s4.y; sv[j+2] = s4.z; sv[j+3] = s4.w;
            dv[j] = d4.x; dv[j+1] = d4.y; dv[j+2] = d4.z; dv[j+3] = d4.w;
        } else {
#pragma unroll
            for (int i = 0; i < 4; ++i) {
                int e = base + j + i;
                sv[j+i] = (e < NE) ? src[e] : -1;
                dv[j+i] = (e < NE) ? dst[e] : 0;
            }
        }
    }
#pragma unroll
    for (int j = 0; j < 8; ++j)
        if (sv[j] >= 0) atomicAdd(&hist[dv[j] >> 8], 1);
    __syncthreads();
    for (int b = tid; b < NBUK; b += 1024) {
        int h = hist[b];
        gb[b] = h ? atomicAdd(&bfill[b], h) : 0;
        bb[b] = bukp[b];
    }
    __syncthreads();
#pragma unroll
    for (int j = 0; j < 8; ++j) {
        if (sv[j] >= 0) {
            int b = dv[j] >> 8;
            int p = atomicAdd(&ofs[b], 1);
            staged[bb[b] + gb[b] + p] = sv[j] | ((dv[j] & 255) << 17);
        }
    }
}

// per-bucket LDS counting sort -> csr (byte offsets src*128); also emits
// rowp[d] and norm[d] (degree known per-thread here).
__global__ __launch_bounds__(256)
void k_bsort(const int* __restrict__ staged, const int* __restrict__ bukp,
             int* __restrict__ csr, int* __restrict__ rowp,
             float* __restrict__ norm) {
    __shared__ int cnt[256];
    __shared__ int wsum[4];
    int b = blockIdx.x, tid = threadIdx.x;
    int lo = bukp[b], hi = bukp[b + 1];
    cnt[tid] = 0;
    __syncthreads();
    for (int i = lo + tid; i < hi; i += 256)
        atomicAdd(&cnt[(staged[i] >> 17) & 255], 1);
    __syncthreads();
    int c = cnt[tid];
    int lane = tid & 63, w = tid >> 6;
    int inc = c;
    for (int o = 1; o < 64; o <<= 1) {
        int u = __shfl_up(inc, o, 64);
        if (lane >= o) inc += u;
    }
    if (lane == 63) wsum[w] = inc;
    __syncthreads();
    int woff = 0;
#pragma unroll
    for (int i = 0; i < 4; ++i) if (i < w) woff += wsum[i];
    int ex = woff + inc - c;
    int node = (b << 8) + tid;
    if (node < NN) {
        rowp[node] = lo + ex;
        int d = (c < 1) ? 1 : c;
        norm[node] = rsqrtf((float)d);
    }
    if (b == 0 && tid == 0) rowp[NN] = NE;
    __syncthreads();
    cnt[tid] = ex;
    __syncthreads();
    for (int i = lo + tid; i < hi; i += 256) {
        int u = staged[i];
        int p = atomicAdd(&cnt[(u >> 17) & 255], 1);
        csr[lo + p] = (u & 0x1FFFF) * ROWB;
    }
}

__device__ __forceinline__ int cat_at(int i, const int* __restrict__ tr,
                                      const int* __restrict__ va, const int* __restrict__ te) {
    if (i < NTR)        return tr[i];
    if (i < NTR + NVA)  return va[i - NTR];
    return te[i - NTR - NVA];
}

// inverse permutation: inv[cat[i]] = i
__global__ void k_inv(const int* __restrict__ tr, const int* __restrict__ va,
                      const int* __restrict__ te, int* __restrict__ inv) {
    int i = blockIdx.x * blockDim.x + threadIdx.x;
    if (i < NN) inv[cat_at(i, tr, va, te)] = i;
}

// ---------- error build + sigma (two-stage, no global atomics) ----------
__global__ void k_error(const float* __restrict__ y_soft, const int* __restrict__ y_true,
                        const int* __restrict__ train, const float* __restrict__ norm,
                        __half* __restrict__ A, __half* __restrict__ last,
                        float* __restrict__ partial) {
    int t = blockIdx.x * blockDim.x + threadIdx.x;
    float a = 0.f;
    if (t < NTR * 12) {
        int j = t / 12, ch = (t % 12) * 4;
        int yt = y_true[j];
        float4 ys = *reinterpret_cast<const float4*>(y_soft + (size_t)j * NC + ch);
        float e0 = ((ch + 0 == yt) ? 1.f : 0.f) - ys.x;
        float e1 = ((ch + 1 == yt) ? 1.f : 0.f) - ys.y;
        float e2 = ((ch + 2 == yt) ? 1.f : 0.f) - ys.z;
        float e3 = ((ch + 3 == yt) ? 1.f : 0.f) - ys.w;
        int r = train[j];
        float w = norm[r];
        *reinterpret_cast<uint2*>(A + (size_t)r * ROWH + ch) =
            f4h(make_float4(w * e0, w * e1, w * e2, w * e3));
        float la = 1.0f - ALPHA1;
        *reinterpret_cast<uint2*>(last + (size_t)r * ROWH + ch) =
            f4h(make_float4(la * e0, la * e1, la * e2, la * e3));
        a = fabsf(e0) + fabsf(e1) + fabsf(e2) + fabsf(e3);
    }
    for (int o = 32; o > 0; o >>= 1) a += __shfl_down(a, o, 64);
    __shared__ float sh[4];
    if ((threadIdx.x & 63) == 0) sh[threadIdx.x >> 6] = a;
    __syncthreads();
    if (threadIdx.x == 0) partial[blockIdx.x] = sh[0] + sh[1] + sh[2] + sh[3];
}

__global__ void k_sigsum(const float* __restrict__ partial, float* __restrict__ sig) {
    float a = 0.f;
    for (int i = threadIdx.x; i < NEB; i += 512) a += partial[i];
    for (int o = 32; o > 0; o >>= 1) a += __shfl_down(a, o, 64);
    __shared__ float sh[8];
    if ((threadIdx.x & 63) == 0) sh[threadIdx.x >> 6] = a;
    __syncthreads();
    if (threadIdx.x == 0) {
        float s = 0.f;
#pragma unroll
        for (int i = 0; i < 8; ++i) s += sh[i];
        sig[0] = s;
    }
}

// ---------- propagation layer (flat loop, unroll-8) ----------
// OUTF: final phase-2 layer writes f32 directly to d_out[inv[node]].
template <bool PRE, bool OUTF>
__global__ __launch_bounds__(256)
void k_gather(const __half* __restrict__ yin, __half* __restrict__ yout,
              const __half* __restrict__ last, const float* __restrict__ norm,
              const int* __restrict__ rowp, const int* __restrict__ csrB,
              float alpha, float lo, float hi,
              float* __restrict__ outF, const int* __restrict__ inv) {
    int t = blockIdx.x * blockDim.x + threadIdx.x;
    if (t >= NN * 6) return;
    int node = t / 6, chb = (t % 6) * 16;
    const char* yb = reinterpret_cast<const char*>(yin) + chb;
    int beg = rowp[node], end = rowp[node + 1];
    float4 A0 = make_float4(0, 0, 0, 0), B0 = make_float4(0, 0, 0, 0);
    float4 A1 = make_float4(0, 0, 0, 0), B1 = make_float4(0, 0, 0, 0);
    int k = beg;
    for (; k + 8 <= end; k += 8) {
        int o0 = csrB[k],     o1 = csrB[k + 1], o2 = csrB[k + 2], o3 = csrB[k + 3];
        int o4 = csrB[k + 4], o5 = csrB[k + 5], o6 = csrB[k + 6], o7 = csrB[k + 7];
        uint4 q0 = *reinterpret_cast<const uint4*>(yb + o0);
        uint4 q1 = *reinterpret_cast<const uint4*>(yb + o1);
        uint4 q2 = *reinterpret_cast<const uint4*>(yb + o2);
        uint4 q3 = *reinterpret_cast<const uint4*>(yb + o3);
        uint4 q4 = *reinterpret_cast<const uint4*>(yb + o4);
        uint4 q5 = *reinterpret_cast<const uint4*>(yb + o5);
        uint4 q6 = *reinterpret_cast<const uint4*>(yb + o6);
        uint4 q7 = *reinterpret_cast<const uint4*>(yb + o7);
        h8acc(q0, A0, B0); h8acc(q1, A1, B1);
        h8acc(q2, A0, B0); h8acc(q3, A1, B1);
        h8acc(q4, A0, B0); h8acc(q5, A1, B1);
        h8acc(q6, A0, B0); h8acc(q7, A1, B1);
    }
    for (; k < end; ++k) {
        uint4 q = *reinterpret_cast<const uint4*>(yb + csrB[k]);
        h8acc(q, A0, B0);
    }
    A0.x += A1.x; A0.y += A1.y; A0.z += A1.z; A0.w += A1.w;
    B0.x += B1.x; B0.y += B1.y; B0.z += B1.z; B0.w += B1.w;

    float nd = alpha * norm[node];
    const char* lb = reinterpret_cast<const char*>(last) + (size_t)node * ROWB + chb;
    H8 lt; lt.u = *reinterpret_cast<const uint4*>(lb);
    float2 l0 = __half22float2(lt.h[0]), l1 = __half22float2(lt.h[1]);
    float2 l2 = __half22float2(lt.h[2]), l3 = __half22float2(lt.h[3]);
    float o0 = fminf(fmaxf(fmaf(nd, A0.x, l0.x), lo), hi);
    float o1 = fminf(fmaxf(fmaf(nd, A0.y, l0.y), lo), hi);
    float o2 = fminf(fmaxf(fmaf(nd, A0.z, l1.x), lo), hi);
    float o3 = fminf(fmaxf(fmaf(nd, A0.w, l1.y), lo), hi);
    float o4 = fminf(fmaxf(fmaf(nd, B0.x, l2.x), lo), hi);
    float o5 = fminf(fmaxf(fmaf(nd, B0.y, l2.y), lo), hi);
    float o6 = fminf(fmaxf(fmaf(nd, B0.z, l3.x), lo), hi);
    float o7 = fminf(fmaxf(fmaf(nd, B0.w, l3.y), lo), hi);
    if (PRE) {
        float w = norm[node];
        o0 *= w; o1 *= w; o2 *= w; o3 *= w; o4 *= w; o5 *= w; o6 *= w; o7 *= w;
    }
    if (OUTF) {
        float* op = outF + (size_t)inv[node] * NC + (t % 6) * 8;
        *reinterpret_cast<float4*>(op)     = make_float4(o0, o1, o2, o3);
        *reinterpret_cast<float4*>(op + 4) = make_float4(o4, o5, o6, o7);
    } else {
        H8 ot;
        ot.h[0] = __float22half2_rn(make_float2(o0, o1));
        ot.h[1] = __float22half2_rn(make_float2(o2, o3));
        ot.h[2] = __float22half2_rn(make_float2(o4, o5));
        ot.h[3] = __float22half2_rn(make_float2(o6, o7));
        char* ob = reinterpret_cast<char*>(yout) + (size_t)node * ROWB + chb;
        *reinterpret_cast<uint4*>(ob) = ot.u;
    }
}

// ---------- scale prep ----------
__global__ void k_rowabs(const __half* __restrict__ se, float* __restrict__ rowabs) {
    int v = blockIdx.x * blockDim.x + threadIdx.x;
    if (v >= NN) return;
    const uint4* p = reinterpret_cast<const uint4*>(se + (size_t)v * ROWH);
    float s = 0.f;
#pragma unroll
    for (int k = 0; k < 6; ++k) {
        H8 t; t.u = p[k];
        float2 f0 = __half22float2(t.h[0]), f1 = __half22float2(t.h[1]);
        float2 f2 = __half22float2(t.h[2]), f3 = __half22float2(t.h[3]);
        s += fabsf(f0.x) + fabsf(f0.y) + fabsf(f1.x) + fabsf(f1.y)
           + fabsf(f2.x) + fabsf(f2.y) + fabsf(f3.x) + fabsf(f3.y);
    }
    rowabs[v] = s;
}

// In-place on A (unscaled smoothed_error in, pre-scaled y_all out).
__global__ void k_phaseD(__half* __restrict__ se_yall, const float* __restrict__ y_soft,
                         const float* __restrict__ rowabs, const float* __restrict__ sig,
                         const int* __restrict__ y_true,
                         const int* __restrict__ tr, const int* __restrict__ va,
                         const int* __restrict__ te, const float* __restrict__ norm,
                         __half* __restrict__ last) {
    int t = blockIdx.x * blockDim.x + threadIdx.x;
    if (t >= NN * 12) return;
    int i = t / 12, ch = (t % 12) * 4;
    int cid = cat_at(i, tr, va, te);
    float4 o;
    if (i < NTR) {
        int yt = y_true[i];
        o.x = (ch + 0 == yt) ? 1.f : 0.f;
        o.y = (ch + 1 == yt) ? 1.f : 0.f;
        o.z = (ch + 2 == yt) ? 1.f : 0.f;
        o.w = (ch + 3 == yt) ? 1.f : 0.f;
    } else {
        float s = (sig[0] * (1.0f / NTR)) / rowabs[i];
        if (s > 1000.0f) s = 1.0f;
        float4 e  = h4f(*reinterpret_cast<const uint2*>(se_yall + (size_t)cid * ROWH + ch));
        float4 ys = *reinterpret_cast<const float4*>(y_soft + (size_t)i * NC + ch);
        o.x = ys.x + s * e.x; if (o.x != o.x) o.x = ys.x;
        o.y = ys.y + s * e.y; if (o.y != o.y) o.y = ys.y;
        o.z = ys.z + s * e.z; if (o.z != o.z) o.z = ys.z;
        o.w = ys.w + s * e.w; if (o.w != o.w) o.w = ys.w;
    }
    float w = norm[cid];
    *reinterpret_cast<uint2*>(se_yall + (size_t)cid * ROWH + ch) =
        f4h(make_float4(o.x * w, o.y * w, o.z * w, o.w * w));
    float la = 1.0f - ALPHA2;
    *reinterpret_cast<uint2*>(last + (size_t)cid * ROWH + ch) =
        f4h(make_float4(la * o.x, la * o.y, la * o.z, la * o.w));
}

extern "C" void kernel_launch(void* const* d_in, const int* in_sizes, int n_in,
                              void* d_out, int out_size, void* d_ws, size_t ws_size,
                              hipStream_t stream) {
    const float* y_soft = (const float*)d_in[0];
    const int*   y_true = (const int*)d_in[1];
    const int*   src    = (const int*)d_in[2];
    const int*   dst    = (const int*)d_in[3];
    const int*   tr     = (const int*)d_in[4];
    const int*   va     = (const int*)d_in[5];
    const int*   te     = (const int*)d_in[6];
    float* out = (float*)d_out;

    char* ws = (char*)d_ws;
    size_t off = 0;
    auto alloc = [&](size_t bytes) -> void* {
        void* p = ws + off;
        off += (bytes + 255) & ~(size_t)255;
        return p;
    };
    __half* A      = (__half*)alloc((size_t)NN * ROWH * 2);   // 12.8 MB
    __half* B      = (__half*)alloc((size_t)NN * ROWH * 2);   // 12.8 MB
    __half* last   = (__half*)alloc((size_t)NN * ROWH * 2);   // 12.8 MB
    int*    csr    = (int*)   alloc((size_t)NE * 4);          // 6.4 MB
    int*    staged = (int*)   alloc((size_t)NE * 4);          // 6.4 MB
    int*    rowp   = (int*)   alloc((size_t)(NN + 1) * 4);
    int*    inv    = (int*)   alloc((size_t)NN * 4);
    int*    bukcnt = (int*)   alloc((size_t)NBUK * 4);
    int*    bukp   = (int*)   alloc((size_t)(NBUK + 1) * 4);
    int*    bfill  = (int*)   alloc((size_t)NBUK * 4);
    float*  norm   = (float*) alloc((size_t)NN * 4);
    float*  rowabs = (float*) alloc((size_t)NN * 4);
    float*  partial= (float*) alloc((size_t)NEB * 4);
    float*  sig    = (float*) alloc(256);

    (void)hipMemsetAsync(bukcnt, 0, (size_t)NBUK * 4, stream);
    (void)hipMemsetAsync(bfill,  0, (size_t)NBUK * 4, stream);
    (void)hipMemsetAsync(A,      0, (size_t)NN * ROWH * 2, stream);
    (void)hipMemsetAsync(last,   0, (size_t)NN * ROWH * 2, stream);

    k_countb <<<NSB, 1024, 0, stream>>>(dst, bukcnt);
    k_bukscan<<<1, 512, 0, stream>>>(bukcnt, bukp);
    k_stage2 <<<NSB, 1024, 0, stream>>>(src, dst, bukp, bfill, staged);
    k_bsort  <<<NBUK, 256, 0, stream>>>(staged, bukp, csr, rowp, norm);
    k_inv    <<<(NN + 255) / 256, 256, 0, stream>>>(tr, va, te, inv);
    k_error  <<<NEB, 256, 0, stream>>>(y_soft, y_true, tr, norm, A, last, partial);
    k_sigsum <<<1, 512, 0, stream>>>(partial, sig);

    const int G6  = (NN * 6 + 255) / 256;
    const int G12 = (NN * 12 + 255) / 256;

    // propagation 1: A -> ... -> A (10 layers); last layer unscaled
    __half* cur = A; __half* oth = B;
    for (int l = 0; l < 10; ++l) {
        if (l < 9)
            k_gather<true, false><<<G6, 256, 0, stream>>>(cur, oth, last, norm, rowp, csr,
                                                          ALPHA1, -1.f, 1.f, nullptr, nullptr);
        else
            k_gather<false, false><<<G6, 256, 0, stream>>>(cur, oth, last, norm, rowp, csr,
                                                           ALPHA1, -1.f, 1.f, nullptr, nullptr);
        __half* t2 = cur; cur = oth; oth = t2;
    }

    k_rowabs<<<(NN + 255) / 256, 256, 0, stream>>>(A, rowabs);
    // in-place: A := norm .* y_all; last := (1-ALPHA2)*y_all
    k_phaseD<<<G12, 256, 0, stream>>>(A, y_soft, rowabs, sig, y_true,
                                      tr, va, te, norm, last);

    // propagation 2: 9 fp16 layers + final layer writes f32 straight to d_out
    cur = A; oth = B;
    for (int l = 0; l < 9; ++l) {
        k_gather<true, false><<<G6, 256, 0, stream>>>(cur, oth, last, norm, rowp, csr,
                                                      ALPHA2, 0.f, 1.f, nullptr, nullptr);
        __half* t2 = cur; cur = oth; oth = t2;
    }
    k_gather<false, true><<<G6, 256, 0, stream>>>(cur, oth, last, norm, rowp, csr,
                                                  ALPHA2, 0.f, 1.f, out, inv);
}